// Round 14
// baseline (1094.865 us; speedup 1.0000x reference)
//
#include <hip/hip_runtime.h>
#include <hip/hip_bf16.h>

// GraphStack: 3x (GCNConv -> GraphNorm), N=100000, E=3.2M, D_IN=128, C=64.
//
// Round 14:
//  - gemm2 register-blocked 2 cols x 8 rows per thread: LDS broadcast reads
//    halved (was the critical path: 512 b128/thread ~ 6144cy > 4096cy FMA).
//  - k_params fused with k_wprime + stats-zeroing (one 64-thread kernel/layer;
//    -2 launches, -2 memsets).
//  - k_pull untouched (~75us: random-gather fabric-bound, 410MB @ ~5.5TB/s).
//  - ELL build: scan-based radix partition (round 13).
//
// d_out (N*64 f32) is the final agg buffer.

#define EPS 1e-5f

__device__ __forceinline__ float bf_lo(unsigned u) {
    union { unsigned u; float f; } c; c.u = u << 16; return c.f;
}
__device__ __forceinline__ float bf_hi(unsigned u) {
    union { unsigned u; float f; } c; c.u = u & 0xffff0000u; return c.f;
}
__device__ __forceinline__ unsigned pack_bf2(float a, float b) {
    union { __hip_bfloat16 h; unsigned short u; } ca, cb;
    ca.h = __float2bfloat16(a);
    cb.h = __float2bfloat16(b);
    return (unsigned)ca.u | ((unsigned)cb.u << 16);
}

// ================= scan-based ELL build =================
__global__ __launch_bounds__(256) void k_hist(const int* __restrict__ dst, int* __restrict__ hist,
                                              int E, int SEG, int NBKT) {
    __shared__ int h[2048];
    int t = threadIdx.x;
    for (int b = t; b < NBKT; b += 256) h[b] = 0;
    __syncthreads();
    int i0 = blockIdx.x * SEG, i1 = min(E, i0 + SEG);
    for (int i = i0 + t * 4; i < i1; i += 1024) {
        if (i + 3 < i1) {
            int4 d = *(const int4*)(dst + i);
            atomicAdd(&h[d.x >> 6], 1);
            atomicAdd(&h[d.y >> 6], 1);
            atomicAdd(&h[d.z >> 6], 1);
            atomicAdd(&h[d.w >> 6], 1);
        } else {
            for (int q = i; q < i1; ++q) atomicAdd(&h[dst[q] >> 6], 1);
        }
    }
    __syncthreads();
    for (int b = t; b < NBKT; b += 256) hist[blockIdx.x * NBKT + b] = h[b];
}

__global__ __launch_bounds__(256) void k_scanA(const int* __restrict__ hist, int* __restrict__ chunkScan,
                                               int* __restrict__ chunkTot, int NBKT, int SCAN_N) {
    __shared__ int ls[256];
    int t = threadIdx.x;
    int base = blockIdx.x * 1024 + t * 4;
    int v[4];
#pragma unroll
    for (int j = 0; j < 4; ++j) {
        int l = base + j;
        v[j] = 0;
        if (l < SCAN_N) {
            int blk = l & 255, bkt = l >> 8;
            v[j] = hist[blk * NBKT + bkt];
        }
    }
    int s = v[0] + v[1] + v[2] + v[3];
    ls[t] = s;
    __syncthreads();
    for (int off = 1; off < 256; off <<= 1) {
        int val = (t >= off) ? ls[t - off] : 0;
        __syncthreads();
        ls[t] += val;
        __syncthreads();
    }
    int run = ls[t] - s;
#pragma unroll
    for (int j = 0; j < 4; ++j) {
        chunkScan[base + j] = run;
        run += v[j];
    }
    if (t == 255) chunkTot[blockIdx.x] = ls[255];
}

__global__ void k_scanB(const int* __restrict__ chunkTot, int* __restrict__ chunkBase, int NCH) {
    __shared__ int s[512];
    int t = threadIdx.x;
    s[t] = (t < NCH) ? chunkTot[t] : 0;
    s[t + 256] = (t + 256 < NCH) ? chunkTot[t + 256] : 0;
    __syncthreads();
    for (int off = 1; off < 512; off <<= 1) {
        int a0 = (t >= off) ? s[t - off] : 0;
        int a1 = (t + 256 >= off) ? s[t + 256 - off] : 0;
        __syncthreads();
        s[t] += a0;
        s[t + 256] += a1;
        __syncthreads();
    }
    if (t < NCH) chunkBase[t] = t ? s[t - 1] : 0;
    if (t + 256 < NCH) chunkBase[t + 256] = s[t + 255];
}

__global__ __launch_bounds__(256) void k_scatter_part(const int* __restrict__ src, const int* __restrict__ dst,
                                                      const int* __restrict__ chunkScan,
                                                      const int* __restrict__ chunkBase,
                                                      int* __restrict__ packed, int E, int SEG, int NBKT) {
    __shared__ int cur[2048];
    int blk = blockIdx.x, t = threadIdx.x;
    for (int b = t; b < NBKT; b += 256) {
        int l = b * 256 + blk;
        cur[b] = chunkScan[l] + chunkBase[l >> 10];
    }
    __syncthreads();
    int i0 = blk * SEG, i1 = min(E, i0 + SEG);
    for (int i = i0 + t * 4; i < i1; i += 1024) {
        if (i + 3 < i1) {
            int4 d = *(const int4*)(dst + i);
            int4 s = *(const int4*)(src + i);
            int p;
            p = atomicAdd(&cur[d.x >> 6], 1); packed[p] = (int)(((unsigned)(d.x & 63) << 26) | (unsigned)s.x);
            p = atomicAdd(&cur[d.y >> 6], 1); packed[p] = (int)(((unsigned)(d.y & 63) << 26) | (unsigned)s.y);
            p = atomicAdd(&cur[d.z >> 6], 1); packed[p] = (int)(((unsigned)(d.z & 63) << 26) | (unsigned)s.z);
            p = atomicAdd(&cur[d.w >> 6], 1); packed[p] = (int)(((unsigned)(d.w & 63) << 26) | (unsigned)s.w);
        } else {
            for (int q = i; q < i1; ++q) {
                int dd = dst[q];
                int p = atomicAdd(&cur[dd >> 6], 1);
                packed[p] = (int)(((unsigned)(dd & 63) << 26) | (unsigned)src[q]);
            }
        }
    }
}

__global__ __launch_bounds__(256) void k_ellfill(const int* __restrict__ packed,
                                                 const int* __restrict__ chunkScan,
                                                 const int* __restrict__ chunkBase,
                                                 int* __restrict__ ell, int* __restrict__ cursor,
                                                 float* __restrict__ dinv,
                                                 int CAP, int NBKT, int N, int E) {
    __shared__ int ellLoc[64 * 96];
    __shared__ int cnt[64];
    int bkt = blockIdx.x, t = threadIdx.x;
    if (t < 64) cnt[t] = 0;
    __syncthreads();
    int l0 = bkt * 256;
    int bs = chunkScan[l0] + chunkBase[l0 >> 10];
    int be = E;
    if (bkt + 1 < NBKT) {
        int l1 = (bkt + 1) * 256;
        be = chunkScan[l1] + chunkBase[l1 >> 10];
    }
    for (int i = bs + t; i < be; i += 256) {
        unsigned p = (unsigned)packed[i];
        int s = (int)(p & 0x03FFFFFFu);
        int ld = (int)(p >> 26);
        int slot = atomicAdd(&cnt[ld], 1);
        if (slot < CAP) ellLoc[ld * CAP + slot] = s;
    }
    __syncthreads();
    int lo = bkt << 6;
    int total = 64 * CAP;
    for (int idx = t; idx < total; idx += 256) {
        int ld = idx / CAP;
        int s = idx - ld * CAP;
        if (lo + ld < N && s < min(cnt[ld], CAP))
            ell[(size_t)lo * CAP + idx] = ellLoc[idx];
    }
    if (t < 64 && lo + t < N) {
        int dg = min(cnt[t], CAP);
        cursor[lo + t] = (lo + t) * CAP + dg;
        dinv[lo + t] = rsqrtf(1.0f + (float)cnt[t]);
    }
}

// ================= fallback ELL build (atomic path) =================
__global__ __launch_bounds__(256) void k_cursor_init(int* cursor, int CAP, int n) {
    int i = blockIdx.x * 256 + threadIdx.x;
    if (i < n) cursor[i] = i * CAP;
}

__global__ __launch_bounds__(256) void k_fill_ell(const int* __restrict__ src, const int* __restrict__ dst,
                                                  int* cursor, int* __restrict__ ell, int E,
                                                  int lo, int hi) {
    int i = (blockIdx.x * 256 + threadIdx.x) * 4;
    if (i + 3 < E) {
        int4 d = *(const int4*)(dst + i);
        int4 s = *(const int4*)(src + i);
        if (d.x >= lo && d.x < hi) ell[atomicAdd(&cursor[d.x], 1)] = s.x;
        if (d.y >= lo && d.y < hi) ell[atomicAdd(&cursor[d.y], 1)] = s.y;
        if (d.z >= lo && d.z < hi) ell[atomicAdd(&cursor[d.z], 1)] = s.z;
        if (d.w >= lo && d.w < hi) ell[atomicAdd(&cursor[d.w], 1)] = s.w;
    } else {
        for (int t = i; t < E; ++t) {
            int d = dst[t];
            if (d >= lo && d < hi) ell[atomicAdd(&cursor[d], 1)] = src[t];
        }
    }
}

__global__ __launch_bounds__(256) void k_deg_dinv(const int* __restrict__ cursor, float* dinv, int CAP, int n) {
    int i = blockIdx.x * 256 + threadIdx.x;
    if (i < n) dinv[i] = rsqrtf(1.0f + (float)(cursor[i] - i * CAP));
}

// ---------------- GEMM: out[N][64](bf16) = (in[N][K] @ Wp[K][64] + bb) * dinv[row] ----------------
// Register-blocked: thread = col-pair (cp, cp+32) x 8 rows. Per 4-k step:
// 8 x-b128 LDS broadcasts (shared by 2 cols) + 8 L1-hot W scalars + 64 FMAs.
template <int K, bool BIN>
__global__ __launch_bounds__(256) void gemm2(const void* __restrict__ in_, const float* __restrict__ Wp,
                                             const float* __restrict__ bb, const float* __restrict__ dinv,
                                             __hip_bfloat16* __restrict__ out, int N) {
    constexpr int ROWS = 64;
    __shared__ float xl[ROWS][K + 4];
    int tid = threadIdx.x;
    int cp = tid & 31;   // cols cp, cp+32
    int rg = tid >> 5;   // row group 0..7 -> rows rg*8..rg*8+7
    int r0 = blockIdx.x * ROWS;

    // stage x tile: rows r0..r0+63
    if (!BIN) {
        const float* in = (const float*)in_;
        for (int i = tid; i < ROWS * (K / 4); i += 256) {
            int row = i / (K / 4);
            int kq = (i - row * (K / 4)) << 2;
            int grow = r0 + row;
            float4 v = make_float4(0.f, 0.f, 0.f, 0.f);
            if (grow < N) v = *(const float4*)&in[(size_t)grow * K + kq];
            *(float4*)&xl[row][kq] = v;
        }
    } else {
        const unsigned short* in = (const unsigned short*)in_;
        for (int i = tid; i < ROWS * (K / 8); i += 256) {
            int row = i / (K / 8);
            int k8 = (i - row * (K / 8)) << 3;
            int grow = r0 + row;
            uint4 v = make_uint4(0u, 0u, 0u, 0u);
            if (grow < N) v = *(const uint4*)(in + (size_t)grow * K + k8);
            float4 a = make_float4(bf_lo(v.x), bf_hi(v.x), bf_lo(v.y), bf_hi(v.y));
            float4 bq = make_float4(bf_lo(v.z), bf_hi(v.z), bf_lo(v.w), bf_hi(v.w));
            *(float4*)&xl[row][k8] = a;
            *(float4*)&xl[row][k8 + 4] = bq;
        }
    }
    __syncthreads();

    float acc0[8], acc1[8];
#pragma unroll
    for (int j = 0; j < 8; ++j) { acc0[j] = 0.f; acc1[j] = 0.f; }
    for (int k0 = 0; k0 < K; k0 += 4) {
        float w00 = Wp[(k0 + 0) * 64 + cp], w01 = Wp[(k0 + 0) * 64 + cp + 32];
        float w10 = Wp[(k0 + 1) * 64 + cp], w11 = Wp[(k0 + 1) * 64 + cp + 32];
        float w20 = Wp[(k0 + 2) * 64 + cp], w21 = Wp[(k0 + 2) * 64 + cp + 32];
        float w30 = Wp[(k0 + 3) * 64 + cp], w31 = Wp[(k0 + 3) * 64 + cp + 32];
#pragma unroll
        for (int j = 0; j < 8; ++j) {
            float4 x4 = *(const float4*)&xl[rg * 8 + j][k0];
            acc0[j] = fmaf(x4.x, w00, acc0[j]); acc1[j] = fmaf(x4.x, w01, acc1[j]);
            acc0[j] = fmaf(x4.y, w10, acc0[j]); acc1[j] = fmaf(x4.y, w11, acc1[j]);
            acc0[j] = fmaf(x4.z, w20, acc0[j]); acc1[j] = fmaf(x4.z, w21, acc1[j]);
            acc0[j] = fmaf(x4.w, w30, acc0[j]); acc1[j] = fmaf(x4.w, w31, acc1[j]);
        }
    }
    float bb0 = bb ? bb[cp] : 0.f;
    float bb1 = bb ? bb[cp + 32] : 0.f;
#pragma unroll
    for (int j = 0; j < 8; ++j) {
        int row = r0 + rg * 8 + j;
        if (row < N) {
            float dv = dinv[row];
            out[(size_t)row * 64 + cp]      = __float2bfloat16((acc0[j] + bb0) * dv);
            out[(size_t)row * 64 + cp + 32] = __float2bfloat16((acc1[j] + bb1) * dv);
        }
    }
}

// ---------------- ELL pull: 8-lane group per node, static balanced slots ----------------
template <bool OUT_BF16>
__global__ __launch_bounds__(256, 4) void k_pull(const int* __restrict__ cursor,
                                                 const int* __restrict__ ell,
                                                 const float* __restrict__ dinv,
                                                 const uint4* __restrict__ xwh,  // 8 x uint4 per row
                                                 const float* __restrict__ bias,
                                                 float* __restrict__ aggf,
                                                 __hip_bfloat16* __restrict__ aggh,
                                                 float* __restrict__ sums, float* __restrict__ sumsq,
                                                 int CAP, int N) {
    int tid = threadIdx.x;
    int lane = tid & 63;
    int g = lane >> 3;   // group (node slot) 0..7
    int cl = lane & 7;   // channel slice
    float bs[8];
#pragma unroll
    for (int k = 0; k < 8; ++k) bs[k] = bias[cl * 8 + k];
    float s_acc[8] = {0, 0, 0, 0, 0, 0, 0, 0};
    float q_acc[8] = {0, 0, 0, 0, 0, 0, 0, 0};

    int slot = (blockIdx.x * 4 + (tid >> 6)) * 8 + g;
    int nslots = gridDim.x * 32;
    for (int n = slot; n < N; n += nslots) {
        int beg = n * CAP, end = cursor[n];
        int last = end - 1;
        float acc[8];
        {   // self row (already scaled by dinv[n])
            uint4 v = xwh[(size_t)n * 8 + cl];
            acc[0] = bf_lo(v.x); acc[1] = bf_hi(v.x);
            acc[2] = bf_lo(v.y); acc[3] = bf_hi(v.y);
            acc[4] = bf_lo(v.z); acc[5] = bf_hi(v.z);
            acc[6] = bf_lo(v.w); acc[7] = bf_hi(v.w);
        }
        int i = beg;
        for (; i + 8 <= end; i += 8) {  // full batches: no clamp/cndmask
            int4 ia = *(const int4*)&ell[i];
            int4 ib = *(const int4*)&ell[i + 4];
            uint4 vv[8];
            vv[0] = xwh[(size_t)ia.x * 8 + cl];
            vv[1] = xwh[(size_t)ia.y * 8 + cl];
            vv[2] = xwh[(size_t)ia.z * 8 + cl];
            vv[3] = xwh[(size_t)ia.w * 8 + cl];
            vv[4] = xwh[(size_t)ib.x * 8 + cl];
            vv[5] = xwh[(size_t)ib.y * 8 + cl];
            vv[6] = xwh[(size_t)ib.z * 8 + cl];
            vv[7] = xwh[(size_t)ib.w * 8 + cl];
#pragma unroll
            for (int k = 0; k < 8; ++k) {
                acc[0] += bf_lo(vv[k].x); acc[1] += bf_hi(vv[k].x);
                acc[2] += bf_lo(vv[k].y); acc[3] += bf_hi(vv[k].y);
                acc[4] += bf_lo(vv[k].z); acc[5] += bf_hi(vv[k].z);
                acc[6] += bf_lo(vv[k].w); acc[7] += bf_hi(vv[k].w);
            }
        }
        if (i < end) {  // tail batch (1..7 edges): clamp + zero
            int4 ia = *(const int4*)&ell[i];
            int4 ib = *(const int4*)&ell[i + 4];
            int ss[8];
            ss[0] = ia.x; ss[1] = ia.y; ss[2] = ia.z; ss[3] = ia.w;
            ss[4] = ib.x; ss[5] = ib.y; ss[6] = ib.z; ss[7] = ib.w;
#pragma unroll
            for (int k = 0; k < 8; ++k) ss[k] = (i + k <= last) ? ss[k] : 0;
            uint4 vv[8];
#pragma unroll
            for (int k = 0; k < 8; ++k) vv[k] = xwh[(size_t)ss[k] * 8 + cl];
#pragma unroll
            for (int k = 0; k < 8; ++k) {
                if (i + k > last) { vv[k].x = 0; vv[k].y = 0; vv[k].z = 0; vv[k].w = 0; }
                acc[0] += bf_lo(vv[k].x); acc[1] += bf_hi(vv[k].x);
                acc[2] += bf_lo(vv[k].y); acc[3] += bf_hi(vv[k].y);
                acc[4] += bf_lo(vv[k].z); acc[5] += bf_hi(vv[k].z);
                acc[6] += bf_lo(vv[k].w); acc[7] += bf_hi(vv[k].w);
            }
        }
        float dn = dinv[n];
        float r[8];
#pragma unroll
        for (int k = 0; k < 8; ++k) {
            r[k] = dn * acc[k] + bs[k];
            s_acc[k] += r[k];
            q_acc[k] += r[k] * r[k];
        }
        if (OUT_BF16) {
            uint4 o;
            o.x = pack_bf2(r[0], r[1]);
            o.y = pack_bf2(r[2], r[3]);
            o.z = pack_bf2(r[4], r[5]);
            o.w = pack_bf2(r[6], r[7]);
            *(uint4*)((unsigned short*)aggh + (size_t)n * 64 + cl * 8) = o;
        } else {
            float4* d4 = (float4*)(aggf + (size_t)n * 64 + cl * 8);
            d4[0] = make_float4(r[0], r[1], r[2], r[3]);
            d4[1] = make_float4(r[4], r[5], r[6], r[7]);
        }
    }

    // block-level stats reduce
    __shared__ float lsum[256][9], lsq[256][9];
#pragma unroll
    for (int k = 0; k < 8; ++k) { lsum[tid][k] = s_acc[k]; lsq[tid][k] = q_acc[k]; }
    __syncthreads();
    if (tid < 64) {
        int cl_t = tid >> 3, k_t = tid & 7;
        float s = 0.f, q = 0.f;
        for (int j = 0; j < 32; ++j) {
            int l = cl_t + 8 * j;
            s += lsum[l][k_t];
            q += lsq[l][k_t];
        }
        atomicAdd(&sums[tid], s);
        atomicAdd(&sumsq[tid], q);
    }
}

// ---------------- GraphNorm params + folded next-layer weights + stat zeroing ----------------
// scale/shift from stats; if W != null also Wp[k][c]=scale[k]W[k][c], bb[c]=sum shift[k]W[k][c].
// Zeroes sums/sumsq (contiguous 128 floats) for the next k_pull.
__global__ void k_params2(float* __restrict__ sums, float* __restrict__ sumsq,
                          const float* __restrict__ alpha, const float* __restrict__ gamma,
                          const float* __restrict__ beta, const float* __restrict__ W,
                          float* __restrict__ scale, float* __restrict__ shift,
                          float* __restrict__ Wp, float* __restrict__ bb, int N) {
    __shared__ float ssc[64], ssh[64];
    int c = threadIdx.x;  // 64 threads
    float invN = 1.0f / (float)N;
    float m = sums[c] * invN;
    float ex2 = sumsq[c] * invN;
    float a = alpha[c];
    float var = ex2 - 2.0f * a * m * m + a * a * m * m;
    float sc = gamma[c] * rsqrtf(var + EPS);
    float sh = beta[c] - sc * a * m;
    scale[c] = sc;
    shift[c] = sh;
    ssc[c] = sc;
    ssh[c] = sh;
    sums[c] = 0.f;   // reset stats for next layer's pull
    sumsq[c] = 0.f;
    __syncthreads();
    if (W) {
        float acc = 0.f;
        for (int k = 0; k < 64; ++k) {
            float w = W[k * 64 + c];
            Wp[k * 64 + c] = ssc[k] * w;
            acc += ssh[k] * w;
        }
        bb[c] = acc;
    }
}

__global__ __launch_bounds__(256) void k_final(float* __restrict__ out, const float* __restrict__ scale,
                                               const float* __restrict__ shift, int n64) {
    int i = blockIdx.x * 256 + threadIdx.x;
    if (i < n64) out[i] = scale[i & 63] * out[i] + shift[i & 63];
}

extern "C" void kernel_launch(void* const* d_in, const int* in_sizes, int n_in,
                              void* d_out, int out_size, void* d_ws, size_t ws_size,
                              hipStream_t stream) {
    const float* x     = (const float*)d_in[0];
    const int*   ei    = (const int*)d_in[1];
    const float* W0    = (const float*)d_in[2];
    const float* Wsp   = (const float*)d_in[3];
    const float* b     = (const float*)d_in[4];
    const float* alpha = (const float*)d_in[5];
    const float* gamma = (const float*)d_in[6];
    const float* beta  = (const float*)d_in[7];

    const int N = in_sizes[0] / 128;  // 100000
    const int E = in_sizes[1] / 2;    // 3200000
    const int* src = ei;
    const int* dst = ei + E;

    float* aggf = (float*)d_out;  // N*64 fp32: final-layer agg / output

    const int Na = ((N + 63) / 64) * 64;
    float* ws = (float*)d_ws;
    size_t off = 0;  // in 4-byte units
    float* dinv  = ws + off; off += Na;
    __hip_bfloat16* xwh = (__hip_bfloat16*)(ws + off); off += (size_t)Na * 32;  // N*64 bf16
    __hip_bfloat16* hb  = (__hip_bfloat16*)(ws + off); off += (size_t)Na * 32;  // N*64 bf16 agg (layers 0,1)
    float* sums  = ws + off; off += 64;
    float* sumsq = ws + off; off += 64;
    float* scbuf = ws + off; off += 64;
    float* shbuf = ws + off; off += 64;
    float* Wp    = ws + off; off += 64 * 64;
    float* bbv   = ws + off; off += 64;
    int* cursor  = (int*)(ws + off); off += Na;

    int CAP = 96;
    while (CAP > 72 && (off + (size_t)N * CAP + 8) * 4 > ws_size) CAP -= 8;
    int* ell = (int*)(ws + off); off += (size_t)N * CAP + 8;

    const int n64 = N * 64;
    const int RB = (N + 63) / 64;
    const int NB = (N + 255) / 256;
    const int PB = (N + 63) / 64;  // k_pull: 2 nodes/slot

    // ----- ELL build: scan-based radix partition (no global atomics) -----
    const int NBKT = (N + 63) >> 6;
    const int NSEG = 256;
    int SEG = ((E + NSEG - 1) / NSEG + 3) & ~3;
    const int SCAN_N = NBKT * 256;
    const int NCH = (SCAN_N + 1023) / 1024;
    int* packed    = (int*)xwh;
    int* hist      = (int*)hb;
    int* chunkScan = hist + (size_t)NSEG * NBKT;
    int* chunkTot  = chunkScan + (size_t)NCH * 1024;
    int* chunkBase = chunkTot + NCH;
    bool fast_build = (NBKT <= 2048) && (NCH <= 512) && (N < (1 << 26)) &&
                      ((size_t)E <= (size_t)Na * 32) &&
                      ((size_t)NSEG * NBKT + (size_t)NCH * 1024 + 2 * NCH <= (size_t)Na * 32);

    if (fast_build) {
        k_hist<<<NSEG, 256, 0, stream>>>(dst, hist, E, SEG, NBKT);
        k_scanA<<<NCH, 256, 0, stream>>>(hist, chunkScan, chunkTot, NBKT, SCAN_N);
        k_scanB<<<1, 256, 0, stream>>>(chunkTot, chunkBase, NCH);
        k_scatter_part<<<NSEG, 256, 0, stream>>>(src, dst, chunkScan, chunkBase, packed, E, SEG, NBKT);
        k_ellfill<<<NBKT, 256, 0, stream>>>(packed, chunkScan, chunkBase, ell, cursor, dinv,
                                            CAP, NBKT, N, E);
    } else {
        k_cursor_init<<<NB, 256, 0, stream>>>(cursor, CAP, N);
        const int NCHUNK = 10;
        int cs = (N + NCHUNK - 1) / NCHUNK;
        const int EB4 = (E / 4 + 255) / 256;
        for (int c = 0; c < NCHUNK; ++c) {
            int lo = c * cs, hi = min(N, lo + cs);
            k_fill_ell<<<EB4, 256, 0, stream>>>(src, dst, cursor, ell, E, lo, hi);
        }
        k_deg_dinv<<<NB, 256, 0, stream>>>(cursor, dinv, CAP, N);
    }

    // stats zero once; k_params2 re-zeroes for subsequent layers
    hipMemsetAsync(sums, 0, 128 * sizeof(float), stream);

    // ----- 3 layers -----
    for (int layer = 0; layer < 3; ++layer) {
        if (layer == 0) {
            gemm2<128, false><<<RB, 256, 0, stream>>>(x, W0, nullptr, dinv, xwh, N);
        } else {
            gemm2<64, true><<<RB, 256, 0, stream>>>(hb, Wp, bbv, dinv, xwh, N);
        }
        if (layer < 2) {
            k_pull<true><<<PB, 256, 0, stream>>>(cursor, ell, dinv, (const uint4*)xwh,
                                                 b + layer * 64, nullptr, hb,
                                                 sums, sumsq, CAP, N);
        } else {
            k_pull<false><<<PB, 256, 0, stream>>>(cursor, ell, dinv, (const uint4*)xwh,
                                                  b + layer * 64, aggf, nullptr,
                                                  sums, sumsq, CAP, N);
        }
        // params + (fold into next layer's weights) + stat re-zero
        const float* Wnext = (layer < 2) ? (Wsp + (size_t)layer * 64 * 64) : nullptr;
        k_params2<<<1, 64, 0, stream>>>(sums, sumsq, alpha + layer * 64, gamma + layer * 64,
                                        beta + layer * 64, Wnext, scbuf, shbuf, Wp, bbv, N);
    }
    k_final<<<(n64 + 255) / 256, 256, 0, stream>>>(aggf, scbuf, shbuf, n64);
}

// Round 15
// 411.955 us; speedup vs baseline: 2.6577x; 2.6577x over previous
//
#include <hip/hip_runtime.h>
#include <hip/hip_bf16.h>

// GraphStack: 3x (GCNConv -> GraphNorm), N=100000, E=3.2M, D_IN=128, C=64.
//
// Round 15:
//  - REVERT round-14 register-blocked gemm2 (VGPR 256 + 417MB scratch spills):
//    back to round-13 gemm2 (1 col x 16 rows, 4 L1-hot W scalars per k-step,
//    VGPR 88, no spills). Lesson: 8 indep global loads/step + full unroll
//    let the scheduler hoist loads until regalloc exploded.
//  - KEPT from round 14: k_params2 fusion (params + weight-fold + stat-zero,
//    one 64-thread launch per layer), scan-based ELL build, 2-nodes/slot pull.
//
// d_out (N*64 f32) is the final agg buffer.

#define EPS 1e-5f

__device__ __forceinline__ float bf_lo(unsigned u) {
    union { unsigned u; float f; } c; c.u = u << 16; return c.f;
}
__device__ __forceinline__ float bf_hi(unsigned u) {
    union { unsigned u; float f; } c; c.u = u & 0xffff0000u; return c.f;
}
__device__ __forceinline__ unsigned pack_bf2(float a, float b) {
    union { __hip_bfloat16 h; unsigned short u; } ca, cb;
    ca.h = __float2bfloat16(a);
    cb.h = __float2bfloat16(b);
    return (unsigned)ca.u | ((unsigned)cb.u << 16);
}

// ================= scan-based ELL build =================
__global__ __launch_bounds__(256) void k_hist(const int* __restrict__ dst, int* __restrict__ hist,
                                              int E, int SEG, int NBKT) {
    __shared__ int h[2048];
    int t = threadIdx.x;
    for (int b = t; b < NBKT; b += 256) h[b] = 0;
    __syncthreads();
    int i0 = blockIdx.x * SEG, i1 = min(E, i0 + SEG);
    for (int i = i0 + t * 4; i < i1; i += 1024) {
        if (i + 3 < i1) {
            int4 d = *(const int4*)(dst + i);
            atomicAdd(&h[d.x >> 6], 1);
            atomicAdd(&h[d.y >> 6], 1);
            atomicAdd(&h[d.z >> 6], 1);
            atomicAdd(&h[d.w >> 6], 1);
        } else {
            for (int q = i; q < i1; ++q) atomicAdd(&h[dst[q] >> 6], 1);
        }
    }
    __syncthreads();
    for (int b = t; b < NBKT; b += 256) hist[blockIdx.x * NBKT + b] = h[b];
}

__global__ __launch_bounds__(256) void k_scanA(const int* __restrict__ hist, int* __restrict__ chunkScan,
                                               int* __restrict__ chunkTot, int NBKT, int SCAN_N) {
    __shared__ int ls[256];
    int t = threadIdx.x;
    int base = blockIdx.x * 1024 + t * 4;
    int v[4];
#pragma unroll
    for (int j = 0; j < 4; ++j) {
        int l = base + j;
        v[j] = 0;
        if (l < SCAN_N) {
            int blk = l & 255, bkt = l >> 8;
            v[j] = hist[blk * NBKT + bkt];
        }
    }
    int s = v[0] + v[1] + v[2] + v[3];
    ls[t] = s;
    __syncthreads();
    for (int off = 1; off < 256; off <<= 1) {
        int val = (t >= off) ? ls[t - off] : 0;
        __syncthreads();
        ls[t] += val;
        __syncthreads();
    }
    int run = ls[t] - s;
#pragma unroll
    for (int j = 0; j < 4; ++j) {
        chunkScan[base + j] = run;
        run += v[j];
    }
    if (t == 255) chunkTot[blockIdx.x] = ls[255];
}

__global__ void k_scanB(const int* __restrict__ chunkTot, int* __restrict__ chunkBase, int NCH) {
    __shared__ int s[512];
    int t = threadIdx.x;
    s[t] = (t < NCH) ? chunkTot[t] : 0;
    s[t + 256] = (t + 256 < NCH) ? chunkTot[t + 256] : 0;
    __syncthreads();
    for (int off = 1; off < 512; off <<= 1) {
        int a0 = (t >= off) ? s[t - off] : 0;
        int a1 = (t + 256 >= off) ? s[t + 256 - off] : 0;
        __syncthreads();
        s[t] += a0;
        s[t + 256] += a1;
        __syncthreads();
    }
    if (t < NCH) chunkBase[t] = t ? s[t - 1] : 0;
    if (t + 256 < NCH) chunkBase[t + 256] = s[t + 255];
}

__global__ __launch_bounds__(256) void k_scatter_part(const int* __restrict__ src, const int* __restrict__ dst,
                                                      const int* __restrict__ chunkScan,
                                                      const int* __restrict__ chunkBase,
                                                      int* __restrict__ packed, int E, int SEG, int NBKT) {
    __shared__ int cur[2048];
    int blk = blockIdx.x, t = threadIdx.x;
    for (int b = t; b < NBKT; b += 256) {
        int l = b * 256 + blk;
        cur[b] = chunkScan[l] + chunkBase[l >> 10];
    }
    __syncthreads();
    int i0 = blk * SEG, i1 = min(E, i0 + SEG);
    for (int i = i0 + t * 4; i < i1; i += 1024) {
        if (i + 3 < i1) {
            int4 d = *(const int4*)(dst + i);
            int4 s = *(const int4*)(src + i);
            int p;
            p = atomicAdd(&cur[d.x >> 6], 1); packed[p] = (int)(((unsigned)(d.x & 63) << 26) | (unsigned)s.x);
            p = atomicAdd(&cur[d.y >> 6], 1); packed[p] = (int)(((unsigned)(d.y & 63) << 26) | (unsigned)s.y);
            p = atomicAdd(&cur[d.z >> 6], 1); packed[p] = (int)(((unsigned)(d.z & 63) << 26) | (unsigned)s.z);
            p = atomicAdd(&cur[d.w >> 6], 1); packed[p] = (int)(((unsigned)(d.w & 63) << 26) | (unsigned)s.w);
        } else {
            for (int q = i; q < i1; ++q) {
                int dd = dst[q];
                int p = atomicAdd(&cur[dd >> 6], 1);
                packed[p] = (int)(((unsigned)(dd & 63) << 26) | (unsigned)src[q]);
            }
        }
    }
}

__global__ __launch_bounds__(256) void k_ellfill(const int* __restrict__ packed,
                                                 const int* __restrict__ chunkScan,
                                                 const int* __restrict__ chunkBase,
                                                 int* __restrict__ ell, int* __restrict__ cursor,
                                                 float* __restrict__ dinv,
                                                 int CAP, int NBKT, int N, int E) {
    __shared__ int ellLoc[64 * 96];
    __shared__ int cnt[64];
    int bkt = blockIdx.x, t = threadIdx.x;
    if (t < 64) cnt[t] = 0;
    __syncthreads();
    int l0 = bkt * 256;
    int bs = chunkScan[l0] + chunkBase[l0 >> 10];
    int be = E;
    if (bkt + 1 < NBKT) {
        int l1 = (bkt + 1) * 256;
        be = chunkScan[l1] + chunkBase[l1 >> 10];
    }
    for (int i = bs + t; i < be; i += 256) {
        unsigned p = (unsigned)packed[i];
        int s = (int)(p & 0x03FFFFFFu);
        int ld = (int)(p >> 26);
        int slot = atomicAdd(&cnt[ld], 1);
        if (slot < CAP) ellLoc[ld * CAP + slot] = s;
    }
    __syncthreads();
    int lo = bkt << 6;
    int total = 64 * CAP;
    for (int idx = t; idx < total; idx += 256) {
        int ld = idx / CAP;
        int s = idx - ld * CAP;
        if (lo + ld < N && s < min(cnt[ld], CAP))
            ell[(size_t)lo * CAP + idx] = ellLoc[idx];
    }
    if (t < 64 && lo + t < N) {
        int dg = min(cnt[t], CAP);
        cursor[lo + t] = (lo + t) * CAP + dg;
        dinv[lo + t] = rsqrtf(1.0f + (float)cnt[t]);
    }
}

// ================= fallback ELL build (atomic path) =================
__global__ __launch_bounds__(256) void k_cursor_init(int* cursor, int CAP, int n) {
    int i = blockIdx.x * 256 + threadIdx.x;
    if (i < n) cursor[i] = i * CAP;
}

__global__ __launch_bounds__(256) void k_fill_ell(const int* __restrict__ src, const int* __restrict__ dst,
                                                  int* cursor, int* __restrict__ ell, int E,
                                                  int lo, int hi) {
    int i = (blockIdx.x * 256 + threadIdx.x) * 4;
    if (i + 3 < E) {
        int4 d = *(const int4*)(dst + i);
        int4 s = *(const int4*)(src + i);
        if (d.x >= lo && d.x < hi) ell[atomicAdd(&cursor[d.x], 1)] = s.x;
        if (d.y >= lo && d.y < hi) ell[atomicAdd(&cursor[d.y], 1)] = s.y;
        if (d.z >= lo && d.z < hi) ell[atomicAdd(&cursor[d.z], 1)] = s.z;
        if (d.w >= lo && d.w < hi) ell[atomicAdd(&cursor[d.w], 1)] = s.w;
    } else {
        for (int t = i; t < E; ++t) {
            int d = dst[t];
            if (d >= lo && d < hi) ell[atomicAdd(&cursor[d], 1)] = src[t];
        }
    }
}

__global__ __launch_bounds__(256) void k_deg_dinv(const int* __restrict__ cursor, float* dinv, int CAP, int n) {
    int i = blockIdx.x * 256 + threadIdx.x;
    if (i < n) dinv[i] = rsqrtf(1.0f + (float)(cursor[i] - i * CAP));
}

// ---------------- GEMM: out[N][64](bf16) = (in[N][K] @ Wp[K][64] + bb) * dinv[row] ----------------
// Round-13 version: thread = col c x 16 rows; 4 L1-hot W scalar loads per
// 4-k step; x-tile LDS reads are wave-uniform b128 broadcasts. VGPR ~88.
template <int K, bool BIN>
__global__ __launch_bounds__(256) void gemm2(const void* __restrict__ in_, const float* __restrict__ Wp,
                                             const float* __restrict__ bb, const float* __restrict__ dinv,
                                             __hip_bfloat16* __restrict__ out, int N) {
    constexpr int ROWS = 64;
    __shared__ float xl[ROWS][K + 4];
    int tid = threadIdx.x;
    int c = tid & 63, rg = tid >> 6;
    int r0 = blockIdx.x * ROWS;

    if (!BIN) {
        const float* in = (const float*)in_;
        for (int i = tid; i < ROWS * (K / 4); i += 256) {
            int row = i / (K / 4);
            int kq = (i - row * (K / 4)) << 2;
            int grow = r0 + row;
            float4 v = make_float4(0.f, 0.f, 0.f, 0.f);
            if (grow < N) v = *(const float4*)&in[(size_t)grow * K + kq];
            *(float4*)&xl[row][kq] = v;
        }
    } else {
        const unsigned short* in = (const unsigned short*)in_;
        for (int i = tid; i < ROWS * (K / 8); i += 256) {
            int row = i / (K / 8);
            int k8 = (i - row * (K / 8)) << 3;
            int grow = r0 + row;
            uint4 v = make_uint4(0u, 0u, 0u, 0u);
            if (grow < N) v = *(const uint4*)(in + (size_t)grow * K + k8);
            float4 a = make_float4(bf_lo(v.x), bf_hi(v.x), bf_lo(v.y), bf_hi(v.y));
            float4 bq = make_float4(bf_lo(v.z), bf_hi(v.z), bf_lo(v.w), bf_hi(v.w));
            *(float4*)&xl[row][k8] = a;
            *(float4*)&xl[row][k8 + 4] = bq;
        }
    }
    __syncthreads();

    float acc[16];
#pragma unroll
    for (int j = 0; j < 16; ++j) acc[j] = 0.f;
    for (int k0 = 0; k0 < K; k0 += 4) {
        float w0 = Wp[(k0 + 0) * 64 + c];  // global, L1-hot, coalesced
        float w1 = Wp[(k0 + 1) * 64 + c];
        float w2 = Wp[(k0 + 2) * 64 + c];
        float w3 = Wp[(k0 + 3) * 64 + c];
#pragma unroll
        for (int j = 0; j < 16; ++j) {
            float4 x4 = *(const float4*)&xl[rg * 16 + j][k0];
            acc[j] = fmaf(x4.x, w0, acc[j]);
            acc[j] = fmaf(x4.y, w1, acc[j]);
            acc[j] = fmaf(x4.z, w2, acc[j]);
            acc[j] = fmaf(x4.w, w3, acc[j]);
        }
    }
    float bbv = bb ? bb[c] : 0.f;
#pragma unroll
    for (int j = 0; j < 16; ++j) {
        int row = r0 + rg * 16 + j;
        if (row < N) out[(size_t)row * 64 + c] = __float2bfloat16((acc[j] + bbv) * dinv[row]);
    }
}

// ---------------- ELL pull: 8-lane group per node, static balanced slots ----------------
template <bool OUT_BF16>
__global__ __launch_bounds__(256, 4) void k_pull(const int* __restrict__ cursor,
                                                 const int* __restrict__ ell,
                                                 const float* __restrict__ dinv,
                                                 const uint4* __restrict__ xwh,  // 8 x uint4 per row
                                                 const float* __restrict__ bias,
                                                 float* __restrict__ aggf,
                                                 __hip_bfloat16* __restrict__ aggh,
                                                 float* __restrict__ sums, float* __restrict__ sumsq,
                                                 int CAP, int N) {
    int tid = threadIdx.x;
    int lane = tid & 63;
    int g = lane >> 3;   // group (node slot) 0..7
    int cl = lane & 7;   // channel slice
    float bs[8];
#pragma unroll
    for (int k = 0; k < 8; ++k) bs[k] = bias[cl * 8 + k];
    float s_acc[8] = {0, 0, 0, 0, 0, 0, 0, 0};
    float q_acc[8] = {0, 0, 0, 0, 0, 0, 0, 0};

    int slot = (blockIdx.x * 4 + (tid >> 6)) * 8 + g;
    int nslots = gridDim.x * 32;
    for (int n = slot; n < N; n += nslots) {
        int beg = n * CAP, end = cursor[n];
        int last = end - 1;
        float acc[8];
        {   // self row (already scaled by dinv[n])
            uint4 v = xwh[(size_t)n * 8 + cl];
            acc[0] = bf_lo(v.x); acc[1] = bf_hi(v.x);
            acc[2] = bf_lo(v.y); acc[3] = bf_hi(v.y);
            acc[4] = bf_lo(v.z); acc[5] = bf_hi(v.z);
            acc[6] = bf_lo(v.w); acc[7] = bf_hi(v.w);
        }
        int i = beg;
        for (; i + 8 <= end; i += 8) {  // full batches: no clamp/cndmask
            int4 ia = *(const int4*)&ell[i];
            int4 ib = *(const int4*)&ell[i + 4];
            uint4 vv[8];
            vv[0] = xwh[(size_t)ia.x * 8 + cl];
            vv[1] = xwh[(size_t)ia.y * 8 + cl];
            vv[2] = xwh[(size_t)ia.z * 8 + cl];
            vv[3] = xwh[(size_t)ia.w * 8 + cl];
            vv[4] = xwh[(size_t)ib.x * 8 + cl];
            vv[5] = xwh[(size_t)ib.y * 8 + cl];
            vv[6] = xwh[(size_t)ib.z * 8 + cl];
            vv[7] = xwh[(size_t)ib.w * 8 + cl];
#pragma unroll
            for (int k = 0; k < 8; ++k) {
                acc[0] += bf_lo(vv[k].x); acc[1] += bf_hi(vv[k].x);
                acc[2] += bf_lo(vv[k].y); acc[3] += bf_hi(vv[k].y);
                acc[4] += bf_lo(vv[k].z); acc[5] += bf_hi(vv[k].z);
                acc[6] += bf_lo(vv[k].w); acc[7] += bf_hi(vv[k].w);
            }
        }
        if (i < end) {  // tail batch (1..7 edges): clamp + zero
            int4 ia = *(const int4*)&ell[i];
            int4 ib = *(const int4*)&ell[i + 4];
            int ss[8];
            ss[0] = ia.x; ss[1] = ia.y; ss[2] = ia.z; ss[3] = ia.w;
            ss[4] = ib.x; ss[5] = ib.y; ss[6] = ib.z; ss[7] = ib.w;
#pragma unroll
            for (int k = 0; k < 8; ++k) ss[k] = (i + k <= last) ? ss[k] : 0;
            uint4 vv[8];
#pragma unroll
            for (int k = 0; k < 8; ++k) vv[k] = xwh[(size_t)ss[k] * 8 + cl];
#pragma unroll
            for (int k = 0; k < 8; ++k) {
                if (i + k > last) { vv[k].x = 0; vv[k].y = 0; vv[k].z = 0; vv[k].w = 0; }
                acc[0] += bf_lo(vv[k].x); acc[1] += bf_hi(vv[k].x);
                acc[2] += bf_lo(vv[k].y); acc[3] += bf_hi(vv[k].y);
                acc[4] += bf_lo(vv[k].z); acc[5] += bf_hi(vv[k].z);
                acc[6] += bf_lo(vv[k].w); acc[7] += bf_hi(vv[k].w);
            }
        }
        float dn = dinv[n];
        float r[8];
#pragma unroll
        for (int k = 0; k < 8; ++k) {
            r[k] = dn * acc[k] + bs[k];
            s_acc[k] += r[k];
            q_acc[k] += r[k] * r[k];
        }
        if (OUT_BF16) {
            uint4 o;
            o.x = pack_bf2(r[0], r[1]);
            o.y = pack_bf2(r[2], r[3]);
            o.z = pack_bf2(r[4], r[5]);
            o.w = pack_bf2(r[6], r[7]);
            *(uint4*)((unsigned short*)aggh + (size_t)n * 64 + cl * 8) = o;
        } else {
            float4* d4 = (float4*)(aggf + (size_t)n * 64 + cl * 8);
            d4[0] = make_float4(r[0], r[1], r[2], r[3]);
            d4[1] = make_float4(r[4], r[5], r[6], r[7]);
        }
    }

    // block-level stats reduce
    __shared__ float lsum[256][9], lsq[256][9];
#pragma unroll
    for (int k = 0; k < 8; ++k) { lsum[tid][k] = s_acc[k]; lsq[tid][k] = q_acc[k]; }
    __syncthreads();
    if (tid < 64) {
        int cl_t = tid >> 3, k_t = tid & 7;
        float s = 0.f, q = 0.f;
        for (int j = 0; j < 32; ++j) {
            int l = cl_t + 8 * j;
            s += lsum[l][k_t];
            q += lsq[l][k_t];
        }
        atomicAdd(&sums[tid], s);
        atomicAdd(&sumsq[tid], q);
    }
}

// ---------------- GraphNorm params + folded next-layer weights + stat zeroing ----------------
__global__ void k_params2(float* __restrict__ sums, float* __restrict__ sumsq,
                          const float* __restrict__ alpha, const float* __restrict__ gamma,
                          const float* __restrict__ beta, const float* __restrict__ W,
                          float* __restrict__ scale, float* __restrict__ shift,
                          float* __restrict__ Wp, float* __restrict__ bb, int N) {
    __shared__ float ssc[64], ssh[64];
    int c = threadIdx.x;  // 64 threads
    float invN = 1.0f / (float)N;
    float m = sums[c] * invN;
    float ex2 = sumsq[c] * invN;
    float a = alpha[c];
    float var = ex2 - 2.0f * a * m * m + a * a * m * m;
    float sc = gamma[c] * rsqrtf(var + EPS);
    float sh = beta[c] - sc * a * m;
    scale[c] = sc;
    shift[c] = sh;
    ssc[c] = sc;
    ssh[c] = sh;
    sums[c] = 0.f;   // reset stats for next layer's pull
    sumsq[c] = 0.f;
    __syncthreads();
    if (W) {
        float acc = 0.f;
        for (int k = 0; k < 64; ++k) {
            float w = W[k * 64 + c];
            Wp[k * 64 + c] = ssc[k] * w;
            acc += ssh[k] * w;
        }
        bb[c] = acc;
    }
}

__global__ __launch_bounds__(256) void k_final(float* __restrict__ out, const float* __restrict__ scale,
                                               const float* __restrict__ shift, int n64) {
    int i = blockIdx.x * 256 + threadIdx.x;
    if (i < n64) out[i] = scale[i & 63] * out[i] + shift[i & 63];
}

extern "C" void kernel_launch(void* const* d_in, const int* in_sizes, int n_in,
                              void* d_out, int out_size, void* d_ws, size_t ws_size,
                              hipStream_t stream) {
    const float* x     = (const float*)d_in[0];
    const int*   ei    = (const int*)d_in[1];
    const float* W0    = (const float*)d_in[2];
    const float* Wsp   = (const float*)d_in[3];
    const float* b     = (const float*)d_in[4];
    const float* alpha = (const float*)d_in[5];
    const float* gamma = (const float*)d_in[6];
    const float* beta  = (const float*)d_in[7];

    const int N = in_sizes[0] / 128;  // 100000
    const int E = in_sizes[1] / 2;    // 3200000
    const int* src = ei;
    const int* dst = ei + E;

    float* aggf = (float*)d_out;  // N*64 fp32: final-layer agg / output

    const int Na = ((N + 63) / 64) * 64;
    float* ws = (float*)d_ws;
    size_t off = 0;  // in 4-byte units
    float* dinv  = ws + off; off += Na;
    __hip_bfloat16* xwh = (__hip_bfloat16*)(ws + off); off += (size_t)Na * 32;  // N*64 bf16
    __hip_bfloat16* hb  = (__hip_bfloat16*)(ws + off); off += (size_t)Na * 32;  // N*64 bf16 agg (layers 0,1)
    float* sums  = ws + off; off += 64;
    float* sumsq = ws + off; off += 64;
    float* scbuf = ws + off; off += 64;
    float* shbuf = ws + off; off += 64;
    float* Wp    = ws + off; off += 64 * 64;
    float* bbv   = ws + off; off += 64;
    int* cursor  = (int*)(ws + off); off += Na;

    int CAP = 96;
    while (CAP > 72 && (off + (size_t)N * CAP + 8) * 4 > ws_size) CAP -= 8;
    int* ell = (int*)(ws + off); off += (size_t)N * CAP + 8;

    const int n64 = N * 64;
    const int RB = (N + 63) / 64;
    const int NB = (N + 255) / 256;
    const int PB = (N + 63) / 64;  // k_pull: 2 nodes/slot

    // ----- ELL build: scan-based radix partition (no global atomics) -----
    const int NBKT = (N + 63) >> 6;
    const int NSEG = 256;
    int SEG = ((E + NSEG - 1) / NSEG + 3) & ~3;
    const int SCAN_N = NBKT * 256;
    const int NCH = (SCAN_N + 1023) / 1024;
    int* packed    = (int*)xwh;
    int* hist      = (int*)hb;
    int* chunkScan = hist + (size_t)NSEG * NBKT;
    int* chunkTot  = chunkScan + (size_t)NCH * 1024;
    int* chunkBase = chunkTot + NCH;
    bool fast_build = (NBKT <= 2048) && (NCH <= 512) && (N < (1 << 26)) &&
                      ((size_t)E <= (size_t)Na * 32) &&
                      ((size_t)NSEG * NBKT + (size_t)NCH * 1024 + 2 * NCH <= (size_t)Na * 32);

    if (fast_build) {
        k_hist<<<NSEG, 256, 0, stream>>>(dst, hist, E, SEG, NBKT);
        k_scanA<<<NCH, 256, 0, stream>>>(hist, chunkScan, chunkTot, NBKT, SCAN_N);
        k_scanB<<<1, 256, 0, stream>>>(chunkTot, chunkBase, NCH);
        k_scatter_part<<<NSEG, 256, 0, stream>>>(src, dst, chunkScan, chunkBase, packed, E, SEG, NBKT);
        k_ellfill<<<NBKT, 256, 0, stream>>>(packed, chunkScan, chunkBase, ell, cursor, dinv,
                                            CAP, NBKT, N, E);
    } else {
        k_cursor_init<<<NB, 256, 0, stream>>>(cursor, CAP, N);
        const int NCHUNK = 10;
        int cs = (N + NCHUNK - 1) / NCHUNK;
        const int EB4 = (E / 4 + 255) / 256;
        for (int c = 0; c < NCHUNK; ++c) {
            int lo = c * cs, hi = min(N, lo + cs);
            k_fill_ell<<<EB4, 256, 0, stream>>>(src, dst, cursor, ell, E, lo, hi);
        }
        k_deg_dinv<<<NB, 256, 0, stream>>>(cursor, dinv, CAP, N);
    }

    // stats zero once; k_params2 re-zeroes for subsequent layers
    hipMemsetAsync(sums, 0, 128 * sizeof(float), stream);

    // ----- 3 layers -----
    for (int layer = 0; layer < 3; ++layer) {
        if (layer == 0) {
            gemm2<128, false><<<RB, 256, 0, stream>>>(x, W0, nullptr, dinv, xwh, N);
        } else {
            gemm2<64, true><<<RB, 256, 0, stream>>>(hb, Wp, bbv, dinv, xwh, N);
        }
        if (layer < 2) {
            k_pull<true><<<PB, 256, 0, stream>>>(cursor, ell, dinv, (const uint4*)xwh,
                                                 b + layer * 64, nullptr, hb,
                                                 sums, sumsq, CAP, N);
        } else {
            k_pull<false><<<PB, 256, 0, stream>>>(cursor, ell, dinv, (const uint4*)xwh,
                                                  b + layer * 64, aggf, nullptr,
                                                  sums, sumsq, CAP, N);
        }
        const float* Wnext = (layer < 2) ? (Wsp + (size_t)layer * 64 * 64) : nullptr;
        k_params2<<<1, 64, 0, stream>>>(sums, sumsq, alpha + layer * 64, gamma + layer * 64,
                                        beta + layer * 64, Wnext, scbuf, shbuf, Wp, bbv, N);
    }
    k_final<<<(n64 + 255) / 256, 256, 0, stream>>>(aggf, scbuf, shbuf, n64);
}

// Round 16
// 406.762 us; speedup vs baseline: 2.6917x; 1.0128x over previous
//
#include <hip/hip_runtime.h>
#include <hip/hip_bf16.h>

// GraphStack: 3x (GCNConv -> GraphNorm), N=100000, E=3.2M, D_IN=128, C=64.
//
// Round 16:
//  - gemm2: 2-col register blocking RETRY with bounded resources: W in LDS
//    (row-major, conflict-free), #pragma unroll 2 on k-loop, launch_bounds
//    (256,2). Halves x-tile LDS reads (the r11/r12 critical pipe) without
//    r14's 256-VGPR spill explosion (cause: 8 global loads/step + full unroll).
//  - Rest identical to round 15: scan-based ELL build, 2-nodes/slot k_pull,
//    k_params2 fusion, bf16 agg layers 0/1.
//
// d_out (N*64 f32) is the final agg buffer.

#define EPS 1e-5f

__device__ __forceinline__ float bf_lo(unsigned u) {
    union { unsigned u; float f; } c; c.u = u << 16; return c.f;
}
__device__ __forceinline__ float bf_hi(unsigned u) {
    union { unsigned u; float f; } c; c.u = u & 0xffff0000u; return c.f;
}
__device__ __forceinline__ unsigned pack_bf2(float a, float b) {
    union { __hip_bfloat16 h; unsigned short u; } ca, cb;
    ca.h = __float2bfloat16(a);
    cb.h = __float2bfloat16(b);
    return (unsigned)ca.u | ((unsigned)cb.u << 16);
}

// ================= scan-based ELL build =================
__global__ __launch_bounds__(256) void k_hist(const int* __restrict__ dst, int* __restrict__ hist,
                                              int E, int SEG, int NBKT) {
    __shared__ int h[2048];
    int t = threadIdx.x;
    for (int b = t; b < NBKT; b += 256) h[b] = 0;
    __syncthreads();
    int i0 = blockIdx.x * SEG, i1 = min(E, i0 + SEG);
    for (int i = i0 + t * 4; i < i1; i += 1024) {
        if (i + 3 < i1) {
            int4 d = *(const int4*)(dst + i);
            atomicAdd(&h[d.x >> 6], 1);
            atomicAdd(&h[d.y >> 6], 1);
            atomicAdd(&h[d.z >> 6], 1);
            atomicAdd(&h[d.w >> 6], 1);
        } else {
            for (int q = i; q < i1; ++q) atomicAdd(&h[dst[q] >> 6], 1);
        }
    }
    __syncthreads();
    for (int b = t; b < NBKT; b += 256) hist[blockIdx.x * NBKT + b] = h[b];
}

__global__ __launch_bounds__(256) void k_scanA(const int* __restrict__ hist, int* __restrict__ chunkScan,
                                               int* __restrict__ chunkTot, int NBKT, int SCAN_N) {
    __shared__ int ls[256];
    int t = threadIdx.x;
    int base = blockIdx.x * 1024 + t * 4;
    int v[4];
#pragma unroll
    for (int j = 0; j < 4; ++j) {
        int l = base + j;
        v[j] = 0;
        if (l < SCAN_N) {
            int blk = l & 255, bkt = l >> 8;
            v[j] = hist[blk * NBKT + bkt];
        }
    }
    int s = v[0] + v[1] + v[2] + v[3];
    ls[t] = s;
    __syncthreads();
    for (int off = 1; off < 256; off <<= 1) {
        int val = (t >= off) ? ls[t - off] : 0;
        __syncthreads();
        ls[t] += val;
        __syncthreads();
    }
    int run = ls[t] - s;
#pragma unroll
    for (int j = 0; j < 4; ++j) {
        chunkScan[base + j] = run;
        run += v[j];
    }
    if (t == 255) chunkTot[blockIdx.x] = ls[255];
}

__global__ void k_scanB(const int* __restrict__ chunkTot, int* __restrict__ chunkBase, int NCH) {
    __shared__ int s[512];
    int t = threadIdx.x;
    s[t] = (t < NCH) ? chunkTot[t] : 0;
    s[t + 256] = (t + 256 < NCH) ? chunkTot[t + 256] : 0;
    __syncthreads();
    for (int off = 1; off < 512; off <<= 1) {
        int a0 = (t >= off) ? s[t - off] : 0;
        int a1 = (t + 256 >= off) ? s[t + 256 - off] : 0;
        __syncthreads();
        s[t] += a0;
        s[t + 256] += a1;
        __syncthreads();
    }
    if (t < NCH) chunkBase[t] = t ? s[t - 1] : 0;
    if (t + 256 < NCH) chunkBase[t + 256] = s[t + 255];
}

__global__ __launch_bounds__(256) void k_scatter_part(const int* __restrict__ src, const int* __restrict__ dst,
                                                      const int* __restrict__ chunkScan,
                                                      const int* __restrict__ chunkBase,
                                                      int* __restrict__ packed, int E, int SEG, int NBKT) {
    __shared__ int cur[2048];
    int blk = blockIdx.x, t = threadIdx.x;
    for (int b = t; b < NBKT; b += 256) {
        int l = b * 256 + blk;
        cur[b] = chunkScan[l] + chunkBase[l >> 10];
    }
    __syncthreads();
    int i0 = blk * SEG, i1 = min(E, i0 + SEG);
    for (int i = i0 + t * 4; i < i1; i += 1024) {
        if (i + 3 < i1) {
            int4 d = *(const int4*)(dst + i);
            int4 s = *(const int4*)(src + i);
            int p;
            p = atomicAdd(&cur[d.x >> 6], 1); packed[p] = (int)(((unsigned)(d.x & 63) << 26) | (unsigned)s.x);
            p = atomicAdd(&cur[d.y >> 6], 1); packed[p] = (int)(((unsigned)(d.y & 63) << 26) | (unsigned)s.y);
            p = atomicAdd(&cur[d.z >> 6], 1); packed[p] = (int)(((unsigned)(d.z & 63) << 26) | (unsigned)s.z);
            p = atomicAdd(&cur[d.w >> 6], 1); packed[p] = (int)(((unsigned)(d.w & 63) << 26) | (unsigned)s.w);
        } else {
            for (int q = i; q < i1; ++q) {
                int dd = dst[q];
                int p = atomicAdd(&cur[dd >> 6], 1);
                packed[p] = (int)(((unsigned)(dd & 63) << 26) | (unsigned)src[q]);
            }
        }
    }
}

__global__ __launch_bounds__(256) void k_ellfill(const int* __restrict__ packed,
                                                 const int* __restrict__ chunkScan,
                                                 const int* __restrict__ chunkBase,
                                                 int* __restrict__ ell, int* __restrict__ cursor,
                                                 float* __restrict__ dinv,
                                                 int CAP, int NBKT, int N, int E) {
    __shared__ int ellLoc[64 * 96];
    __shared__ int cnt[64];
    int bkt = blockIdx.x, t = threadIdx.x;
    if (t < 64) cnt[t] = 0;
    __syncthreads();
    int l0 = bkt * 256;
    int bs = chunkScan[l0] + chunkBase[l0 >> 10];
    int be = E;
    if (bkt + 1 < NBKT) {
        int l1 = (bkt + 1) * 256;
        be = chunkScan[l1] + chunkBase[l1 >> 10];
    }
    for (int i = bs + t; i < be; i += 256) {
        unsigned p = (unsigned)packed[i];
        int s = (int)(p & 0x03FFFFFFu);
        int ld = (int)(p >> 26);
        int slot = atomicAdd(&cnt[ld], 1);
        if (slot < CAP) ellLoc[ld * CAP + slot] = s;
    }
    __syncthreads();
    int lo = bkt << 6;
    int total = 64 * CAP;
    for (int idx = t; idx < total; idx += 256) {
        int ld = idx / CAP;
        int s = idx - ld * CAP;
        if (lo + ld < N && s < min(cnt[ld], CAP))
            ell[(size_t)lo * CAP + idx] = ellLoc[idx];
    }
    if (t < 64 && lo + t < N) {
        int dg = min(cnt[t], CAP);
        cursor[lo + t] = (lo + t) * CAP + dg;
        dinv[lo + t] = rsqrtf(1.0f + (float)cnt[t]);
    }
}

// ================= fallback ELL build (atomic path) =================
__global__ __launch_bounds__(256) void k_cursor_init(int* cursor, int CAP, int n) {
    int i = blockIdx.x * 256 + threadIdx.x;
    if (i < n) cursor[i] = i * CAP;
}

__global__ __launch_bounds__(256) void k_fill_ell(const int* __restrict__ src, const int* __restrict__ dst,
                                                  int* cursor, int* __restrict__ ell, int E,
                                                  int lo, int hi) {
    int i = (blockIdx.x * 256 + threadIdx.x) * 4;
    if (i + 3 < E) {
        int4 d = *(const int4*)(dst + i);
        int4 s = *(const int4*)(src + i);
        if (d.x >= lo && d.x < hi) ell[atomicAdd(&cursor[d.x], 1)] = s.x;
        if (d.y >= lo && d.y < hi) ell[atomicAdd(&cursor[d.y], 1)] = s.y;
        if (d.z >= lo && d.z < hi) ell[atomicAdd(&cursor[d.z], 1)] = s.z;
        if (d.w >= lo && d.w < hi) ell[atomicAdd(&cursor[d.w], 1)] = s.w;
    } else {
        for (int t = i; t < E; ++t) {
            int d = dst[t];
            if (d >= lo && d < hi) ell[atomicAdd(&cursor[d], 1)] = src[t];
        }
    }
}

__global__ __launch_bounds__(256) void k_deg_dinv(const int* __restrict__ cursor, float* dinv, int CAP, int n) {
    int i = blockIdx.x * 256 + threadIdx.x;
    if (i < n) dinv[i] = rsqrtf(1.0f + (float)(cursor[i] - i * CAP));
}

// ---------------- GEMM: out[N][64](bf16) = (in[N][K] @ Wp[K][64] + bb) * dinv[row] ----------------
// 2-col register blocking: thread = cols (cp, cp+32) x 8 rows. Per 4-k step:
// 8 x-b128 LDS reads (halved vs 1-col) + 8 conflict-free W b32 LDS reads + 64
// FMA. W in LDS (not global: r14's hoisting trigger); unroll 2 bounds live
// ranges; launch_bounds(256,2) caps VGPR at 128.
template <int K, bool BIN>
__global__ __launch_bounds__(256, 2) void gemm2(const void* __restrict__ in_, const float* __restrict__ Wp,
                                                const float* __restrict__ bb, const float* __restrict__ dinv,
                                                __hip_bfloat16* __restrict__ out, int N) {
    constexpr int ROWS = 64;
    __shared__ float Wl[K * 64];
    __shared__ float xl[ROWS][K + 4];
    int tid = threadIdx.x;
    int cp = tid & 31;   // cols cp, cp+32
    int rg = tid >> 5;   // row group 0..7 -> rows rg*8..rg*8+7
    int r0 = blockIdx.x * ROWS;

    // stage W: contiguous copy, row-major [k][64]
    for (int i = tid; i < K * 16; i += 256)
        *(float4*)&Wl[i * 4] = *(const float4*)&Wp[i * 4];

    // stage x tile: rows r0..r0+63
    if (!BIN) {
        const float* in = (const float*)in_;
        for (int i = tid; i < ROWS * (K / 4); i += 256) {
            int row = i / (K / 4);
            int kq = (i - row * (K / 4)) << 2;
            int grow = r0 + row;
            float4 v = make_float4(0.f, 0.f, 0.f, 0.f);
            if (grow < N) v = *(const float4*)&in[(size_t)grow * K + kq];
            *(float4*)&xl[row][kq] = v;
        }
    } else {
        const unsigned short* in = (const unsigned short*)in_;
        for (int i = tid; i < ROWS * (K / 8); i += 256) {
            int row = i / (K / 8);
            int k8 = (i - row * (K / 8)) << 3;
            int grow = r0 + row;
            uint4 v = make_uint4(0u, 0u, 0u, 0u);
            if (grow < N) v = *(const uint4*)(in + (size_t)grow * K + k8);
            float4 a = make_float4(bf_lo(v.x), bf_hi(v.x), bf_lo(v.y), bf_hi(v.y));
            float4 bq = make_float4(bf_lo(v.z), bf_hi(v.z), bf_lo(v.w), bf_hi(v.w));
            *(float4*)&xl[row][k8] = a;
            *(float4*)&xl[row][k8 + 4] = bq;
        }
    }
    __syncthreads();

    float acc0[8], acc1[8];
#pragma unroll
    for (int j = 0; j < 8; ++j) { acc0[j] = 0.f; acc1[j] = 0.f; }
#pragma unroll 2
    for (int k0 = 0; k0 < K; k0 += 4) {
        float w00 = Wl[(k0 + 0) * 64 + cp], w01 = Wl[(k0 + 0) * 64 + cp + 32];
        float w10 = Wl[(k0 + 1) * 64 + cp], w11 = Wl[(k0 + 1) * 64 + cp + 32];
        float w20 = Wl[(k0 + 2) * 64 + cp], w21 = Wl[(k0 + 2) * 64 + cp + 32];
        float w30 = Wl[(k0 + 3) * 64 + cp], w31 = Wl[(k0 + 3) * 64 + cp + 32];
#pragma unroll
        for (int j = 0; j < 8; ++j) {
            float4 x4 = *(const float4*)&xl[rg * 8 + j][k0];
            acc0[j] = fmaf(x4.x, w00, acc0[j]); acc1[j] = fmaf(x4.x, w01, acc1[j]);
            acc0[j] = fmaf(x4.y, w10, acc0[j]); acc1[j] = fmaf(x4.y, w11, acc1[j]);
            acc0[j] = fmaf(x4.z, w20, acc0[j]); acc1[j] = fmaf(x4.z, w21, acc1[j]);
            acc0[j] = fmaf(x4.w, w30, acc0[j]); acc1[j] = fmaf(x4.w, w31, acc1[j]);
        }
    }
    float bb0 = bb ? bb[cp] : 0.f;
    float bb1 = bb ? bb[cp + 32] : 0.f;
#pragma unroll
    for (int j = 0; j < 8; ++j) {
        int row = r0 + rg * 8 + j;
        if (row < N) {
            float dv = dinv[row];
            out[(size_t)row * 64 + cp]      = __float2bfloat16((acc0[j] + bb0) * dv);
            out[(size_t)row * 64 + cp + 32] = __float2bfloat16((acc1[j] + bb1) * dv);
        }
    }
}

// ---------------- ELL pull: 8-lane group per node, static balanced slots ----------------
template <bool OUT_BF16>
__global__ __launch_bounds__(256, 4) void k_pull(const int* __restrict__ cursor,
                                                 const int* __restrict__ ell,
                                                 const float* __restrict__ dinv,
                                                 const uint4* __restrict__ xwh,  // 8 x uint4 per row
                                                 const float* __restrict__ bias,
                                                 float* __restrict__ aggf,
                                                 __hip_bfloat16* __restrict__ aggh,
                                                 float* __restrict__ sums, float* __restrict__ sumsq,
                                                 int CAP, int N) {
    int tid = threadIdx.x;
    int lane = tid & 63;
    int g = lane >> 3;   // group (node slot) 0..7
    int cl = lane & 7;   // channel slice
    float bs[8];
#pragma unroll
    for (int k = 0; k < 8; ++k) bs[k] = bias[cl * 8 + k];
    float s_acc[8] = {0, 0, 0, 0, 0, 0, 0, 0};
    float q_acc[8] = {0, 0, 0, 0, 0, 0, 0, 0};

    int slot = (blockIdx.x * 4 + (tid >> 6)) * 8 + g;
    int nslots = gridDim.x * 32;
    for (int n = slot; n < N; n += nslots) {
        int beg = n * CAP, end = cursor[n];
        int last = end - 1;
        float acc[8];
        {   // self row (already scaled by dinv[n])
            uint4 v = xwh[(size_t)n * 8 + cl];
            acc[0] = bf_lo(v.x); acc[1] = bf_hi(v.x);
            acc[2] = bf_lo(v.y); acc[3] = bf_hi(v.y);
            acc[4] = bf_lo(v.z); acc[5] = bf_hi(v.z);
            acc[6] = bf_lo(v.w); acc[7] = bf_hi(v.w);
        }
        int i = beg;
        for (; i + 8 <= end; i += 8) {  // full batches: no clamp/cndmask
            int4 ia = *(const int4*)&ell[i];
            int4 ib = *(const int4*)&ell[i + 4];
            uint4 vv[8];
            vv[0] = xwh[(size_t)ia.x * 8 + cl];
            vv[1] = xwh[(size_t)ia.y * 8 + cl];
            vv[2] = xwh[(size_t)ia.z * 8 + cl];
            vv[3] = xwh[(size_t)ia.w * 8 + cl];
            vv[4] = xwh[(size_t)ib.x * 8 + cl];
            vv[5] = xwh[(size_t)ib.y * 8 + cl];
            vv[6] = xwh[(size_t)ib.z * 8 + cl];
            vv[7] = xwh[(size_t)ib.w * 8 + cl];
#pragma unroll
            for (int k = 0; k < 8; ++k) {
                acc[0] += bf_lo(vv[k].x); acc[1] += bf_hi(vv[k].x);
                acc[2] += bf_lo(vv[k].y); acc[3] += bf_hi(vv[k].y);
                acc[4] += bf_lo(vv[k].z); acc[5] += bf_hi(vv[k].z);
                acc[6] += bf_lo(vv[k].w); acc[7] += bf_hi(vv[k].w);
            }
        }
        if (i < end) {  // tail batch (1..7 edges): clamp + zero
            int4 ia = *(const int4*)&ell[i];
            int4 ib = *(const int4*)&ell[i + 4];
            int ss[8];
            ss[0] = ia.x; ss[1] = ia.y; ss[2] = ia.z; ss[3] = ia.w;
            ss[4] = ib.x; ss[5] = ib.y; ss[6] = ib.z; ss[7] = ib.w;
#pragma unroll
            for (int k = 0; k < 8; ++k) ss[k] = (i + k <= last) ? ss[k] : 0;
            uint4 vv[8];
#pragma unroll
            for (int k = 0; k < 8; ++k) vv[k] = xwh[(size_t)ss[k] * 8 + cl];
#pragma unroll
            for (int k = 0; k < 8; ++k) {
                if (i + k > last) { vv[k].x = 0; vv[k].y = 0; vv[k].z = 0; vv[k].w = 0; }
                acc[0] += bf_lo(vv[k].x); acc[1] += bf_hi(vv[k].x);
                acc[2] += bf_lo(vv[k].y); acc[3] += bf_hi(vv[k].y);
                acc[4] += bf_lo(vv[k].z); acc[5] += bf_hi(vv[k].z);
                acc[6] += bf_lo(vv[k].w); acc[7] += bf_hi(vv[k].w);
            }
        }
        float dn = dinv[n];
        float r[8];
#pragma unroll
        for (int k = 0; k < 8; ++k) {
            r[k] = dn * acc[k] + bs[k];
            s_acc[k] += r[k];
            q_acc[k] += r[k] * r[k];
        }
        if (OUT_BF16) {
            uint4 o;
            o.x = pack_bf2(r[0], r[1]);
            o.y = pack_bf2(r[2], r[3]);
            o.z = pack_bf2(r[4], r[5]);
            o.w = pack_bf2(r[6], r[7]);
            *(uint4*)((unsigned short*)aggh + (size_t)n * 64 + cl * 8) = o;
        } else {
            float4* d4 = (float4*)(aggf + (size_t)n * 64 + cl * 8);
            d4[0] = make_float4(r[0], r[1], r[2], r[3]);
            d4[1] = make_float4(r[4], r[5], r[6], r[7]);
        }
    }

    // block-level stats reduce
    __shared__ float lsum[256][9], lsq[256][9];
#pragma unroll
    for (int k = 0; k < 8; ++k) { lsum[tid][k] = s_acc[k]; lsq[tid][k] = q_acc[k]; }
    __syncthreads();
    if (tid < 64) {
        int cl_t = tid >> 3, k_t = tid & 7;
        float s = 0.f, q = 0.f;
        for (int j = 0; j < 32; ++j) {
            int l = cl_t + 8 * j;
            s += lsum[l][k_t];
            q += lsq[l][k_t];
        }
        atomicAdd(&sums[tid], s);
        atomicAdd(&sumsq[tid], q);
    }
}

// ---------------- GraphNorm params + folded next-layer weights + stat zeroing ----------------
__global__ void k_params2(float* __restrict__ sums, float* __restrict__ sumsq,
                          const float* __restrict__ alpha, const float* __restrict__ gamma,
                          const float* __restrict__ beta, const float* __restrict__ W,
                          float* __restrict__ scale, float* __restrict__ shift,
                          float* __restrict__ Wp, float* __restrict__ bb, int N) {
    __shared__ float ssc[64], ssh[64];
    int c = threadIdx.x;  // 64 threads
    float invN = 1.0f / (float)N;
    float m = sums[c] * invN;
    float ex2 = sumsq[c] * invN;
    float a = alpha[c];
    float var = ex2 - 2.0f * a * m * m + a * a * m * m;
    float sc = gamma[c] * rsqrtf(var + EPS);
    float sh = beta[c] - sc * a * m;
    scale[c] = sc;
    shift[c] = sh;
    ssc[c] = sc;
    ssh[c] = sh;
    sums[c] = 0.f;   // reset stats for next layer's pull
    sumsq[c] = 0.f;
    __syncthreads();
    if (W) {
        float acc = 0.f;
        for (int k = 0; k < 64; ++k) {
            float w = W[k * 64 + c];
            Wp[k * 64 + c] = ssc[k] * w;
            acc += ssh[k] * w;
        }
        bb[c] = acc;
    }
}

__global__ __launch_bounds__(256) void k_final(float* __restrict__ out, const float* __restrict__ scale,
                                               const float* __restrict__ shift, int n64) {
    int i = blockIdx.x * 256 + threadIdx.x;
    if (i < n64) out[i] = scale[i & 63] * out[i] + shift[i & 63];
}

extern "C" void kernel_launch(void* const* d_in, const int* in_sizes, int n_in,
                              void* d_out, int out_size, void* d_ws, size_t ws_size,
                              hipStream_t stream) {
    const float* x     = (const float*)d_in[0];
    const int*   ei    = (const int*)d_in[1];
    const float* W0    = (const float*)d_in[2];
    const float* Wsp   = (const float*)d_in[3];
    const float* b     = (const float*)d_in[4];
    const float* alpha = (const float*)d_in[5];
    const float* gamma = (const float*)d_in[6];
    const float* beta  = (const float*)d_in[7];

    const int N = in_sizes[0] / 128;  // 100000
    const int E = in_sizes[1] / 2;    // 3200000
    const int* src = ei;
    const int* dst = ei + E;

    float* aggf = (float*)d_out;  // N*64 fp32: final-layer agg / output

    const int Na = ((N + 63) / 64) * 64;
    float* ws = (float*)d_ws;
    size_t off = 0;  // in 4-byte units
    float* dinv  = ws + off; off += Na;
    __hip_bfloat16* xwh = (__hip_bfloat16*)(ws + off); off += (size_t)Na * 32;  // N*64 bf16
    __hip_bfloat16* hb  = (__hip_bfloat16*)(ws + off); off += (size_t)Na * 32;  // N*64 bf16 agg (layers 0,1)
    float* sums  = ws + off; off += 64;
    float* sumsq = ws + off; off += 64;
    float* scbuf = ws + off; off += 64;
    float* shbuf = ws + off; off += 64;
    float* Wp    = ws + off; off += 64 * 64;
    float* bbv   = ws + off; off += 64;
    int* cursor  = (int*)(ws + off); off += Na;

    int CAP = 96;
    while (CAP > 72 && (off + (size_t)N * CAP + 8) * 4 > ws_size) CAP -= 8;
    int* ell = (int*)(ws + off); off += (size_t)N * CAP + 8;

    const int n64 = N * 64;
    const int RB = (N + 63) / 64;
    const int NB = (N + 255) / 256;
    const int PB = (N + 63) / 64;  // k_pull: 2 nodes/slot

    // ----- ELL build: scan-based radix partition (no global atomics) -----
    const int NBKT = (N + 63) >> 6;
    const int NSEG = 256;
    int SEG = ((E + NSEG - 1) / NSEG + 3) & ~3;
    const int SCAN_N = NBKT * 256;
    const int NCH = (SCAN_N + 1023) / 1024;
    int* packed    = (int*)xwh;
    int* hist      = (int*)hb;
    int* chunkScan = hist + (size_t)NSEG * NBKT;
    int* chunkTot  = chunkScan + (size_t)NCH * 1024;
    int* chunkBase = chunkTot + NCH;
    bool fast_build = (NBKT <= 2048) && (NCH <= 512) && (N < (1 << 26)) &&
                      ((size_t)E <= (size_t)Na * 32) &&
                      ((size_t)NSEG * NBKT + (size_t)NCH * 1024 + 2 * NCH <= (size_t)Na * 32);

    if (fast_build) {
        k_hist<<<NSEG, 256, 0, stream>>>(dst, hist, E, SEG, NBKT);
        k_scanA<<<NCH, 256, 0, stream>>>(hist, chunkScan, chunkTot, NBKT, SCAN_N);
        k_scanB<<<1, 256, 0, stream>>>(chunkTot, chunkBase, NCH);
        k_scatter_part<<<NSEG, 256, 0, stream>>>(src, dst, chunkScan, chunkBase, packed, E, SEG, NBKT);
        k_ellfill<<<NBKT, 256, 0, stream>>>(packed, chunkScan, chunkBase, ell, cursor, dinv,
                                            CAP, NBKT, N, E);
    } else {
        k_cursor_init<<<NB, 256, 0, stream>>>(cursor, CAP, N);
        const int NCHUNK = 10;
        int cs = (N + NCHUNK - 1) / NCHUNK;
        const int EB4 = (E / 4 + 255) / 256;
        for (int c = 0; c < NCHUNK; ++c) {
            int lo = c * cs, hi = min(N, lo + cs);
            k_fill_ell<<<EB4, 256, 0, stream>>>(src, dst, cursor, ell, E, lo, hi);
        }
        k_deg_dinv<<<NB, 256, 0, stream>>>(cursor, dinv, CAP, N);
    }

    // stats zero once; k_params2 re-zeroes for subsequent layers
    hipMemsetAsync(sums, 0, 128 * sizeof(float), stream);

    // ----- 3 layers -----
    for (int layer = 0; layer < 3; ++layer) {
        if (layer == 0) {
            gemm2<128, false><<<RB, 256, 0, stream>>>(x, W0, nullptr, dinv, xwh, N);
        } else {
            gemm2<64, true><<<RB, 256, 0, stream>>>(hb, Wp, bbv, dinv, xwh, N);
        }
        if (layer < 2) {
            k_pull<true><<<PB, 256, 0, stream>>>(cursor, ell, dinv, (const uint4*)xwh,
                                                 b + layer * 64, nullptr, hb,
                                                 sums, sumsq, CAP, N);
        } else {
            k_pull<false><<<PB, 256, 0, stream>>>(cursor, ell, dinv, (const uint4*)xwh,
                                                  b + layer * 64, aggf, nullptr,
                                                  sums, sumsq, CAP, N);
        }
        const float* Wnext = (layer < 2) ? (Wsp + (size_t)layer * 64 * 64) : nullptr;
        k_params2<<<1, 64, 0, stream>>>(sums, sumsq, alpha + layer * 64, gamma + layer * 64,
                                        beta + layer * 64, Wnext, scbuf, shbuf, Wp, bbv, N);
    }
    k_final<<<(n64 + 255) / 256, 256, 0, stream>>>(aggf, scbuf, shbuf, n64);
}

// Round 17
// 385.891 us; speedup vs baseline: 2.8372x; 1.0541x over previous
//
#include <hip/hip_runtime.h>
#include <hip/hip_bf16.h>

// GraphStack: 3x (GCNConv -> GraphNorm), N=100000, E=3.2M, D_IN=128, C=64.
//
// Round 17:
//  - GEMMs moved to MFMA (mfma_f32_16x16x32_bf16), LDS-free: A frags straight
//    from global (L1-hot, lane=row kgroup=lane>>4), B frags from transposed
//    bf16 weight table Wb[col][K] (<=16KB, L1-resident). Epilogue fuses
//    (+bb)*dinv + bf16 pack. fp32 vector gemm was stuck at 4-8x roofline
//    (LDS-occupancy vs VALU corner, r11-r16).
//  - k_params2 emits Wb (bf16 transposed) instead of fp32 Wp; k_packW0 once.
//  - Rest identical to round 16: scan-based ELL build, 2-nodes/slot k_pull,
//    bf16 agg layers 0/1.
//
// d_out (N*64 f32) is the final agg buffer.

#define EPS 1e-5f

typedef __attribute__((ext_vector_type(8))) short bf16x8;
typedef __attribute__((ext_vector_type(4))) float f32x4;

__device__ __forceinline__ float bf_lo(unsigned u) {
    union { unsigned u; float f; } c; c.u = u << 16; return c.f;
}
__device__ __forceinline__ float bf_hi(unsigned u) {
    union { unsigned u; float f; } c; c.u = u & 0xffff0000u; return c.f;
}
__device__ __forceinline__ unsigned pack_bf2(float a, float b) {
    union { __hip_bfloat16 h; unsigned short u; } ca, cb;
    ca.h = __float2bfloat16(a);
    cb.h = __float2bfloat16(b);
    return (unsigned)ca.u | ((unsigned)cb.u << 16);
}
__device__ __forceinline__ short bfb(float f) {
    union { __hip_bfloat16 h; short s; } u; u.h = __float2bfloat16(f); return u.s;
}

// ================= scan-based ELL build =================
__global__ __launch_bounds__(256) void k_hist(const int* __restrict__ dst, int* __restrict__ hist,
                                              int E, int SEG, int NBKT) {
    __shared__ int h[2048];
    int t = threadIdx.x;
    for (int b = t; b < NBKT; b += 256) h[b] = 0;
    __syncthreads();
    int i0 = blockIdx.x * SEG, i1 = min(E, i0 + SEG);
    for (int i = i0 + t * 4; i < i1; i += 1024) {
        if (i + 3 < i1) {
            int4 d = *(const int4*)(dst + i);
            atomicAdd(&h[d.x >> 6], 1);
            atomicAdd(&h[d.y >> 6], 1);
            atomicAdd(&h[d.z >> 6], 1);
            atomicAdd(&h[d.w >> 6], 1);
        } else {
            for (int q = i; q < i1; ++q) atomicAdd(&h[dst[q] >> 6], 1);
        }
    }
    __syncthreads();
    for (int b = t; b < NBKT; b += 256) hist[blockIdx.x * NBKT + b] = h[b];
}

__global__ __launch_bounds__(256) void k_scanA(const int* __restrict__ hist, int* __restrict__ chunkScan,
                                               int* __restrict__ chunkTot, int NBKT, int SCAN_N) {
    __shared__ int ls[256];
    int t = threadIdx.x;
    int base = blockIdx.x * 1024 + t * 4;
    int v[4];
#pragma unroll
    for (int j = 0; j < 4; ++j) {
        int l = base + j;
        v[j] = 0;
        if (l < SCAN_N) {
            int blk = l & 255, bkt = l >> 8;
            v[j] = hist[blk * NBKT + bkt];
        }
    }
    int s = v[0] + v[1] + v[2] + v[3];
    ls[t] = s;
    __syncthreads();
    for (int off = 1; off < 256; off <<= 1) {
        int val = (t >= off) ? ls[t - off] : 0;
        __syncthreads();
        ls[t] += val;
        __syncthreads();
    }
    int run = ls[t] - s;
#pragma unroll
    for (int j = 0; j < 4; ++j) {
        chunkScan[base + j] = run;
        run += v[j];
    }
    if (t == 255) chunkTot[blockIdx.x] = ls[255];
}

__global__ void k_scanB(const int* __restrict__ chunkTot, int* __restrict__ chunkBase, int NCH) {
    __shared__ int s[512];
    int t = threadIdx.x;
    s[t] = (t < NCH) ? chunkTot[t] : 0;
    s[t + 256] = (t + 256 < NCH) ? chunkTot[t + 256] : 0;
    __syncthreads();
    for (int off = 1; off < 512; off <<= 1) {
        int a0 = (t >= off) ? s[t - off] : 0;
        int a1 = (t + 256 >= off) ? s[t + 256 - off] : 0;
        __syncthreads();
        s[t] += a0;
        s[t + 256] += a1;
        __syncthreads();
    }
    if (t < NCH) chunkBase[t] = t ? s[t - 1] : 0;
    if (t + 256 < NCH) chunkBase[t + 256] = s[t + 255];
}

__global__ __launch_bounds__(256) void k_scatter_part(const int* __restrict__ src, const int* __restrict__ dst,
                                                      const int* __restrict__ chunkScan,
                                                      const int* __restrict__ chunkBase,
                                                      int* __restrict__ packed, int E, int SEG, int NBKT) {
    __shared__ int cur[2048];
    int blk = blockIdx.x, t = threadIdx.x;
    for (int b = t; b < NBKT; b += 256) {
        int l = b * 256 + blk;
        cur[b] = chunkScan[l] + chunkBase[l >> 10];
    }
    __syncthreads();
    int i0 = blk * SEG, i1 = min(E, i0 + SEG);
    for (int i = i0 + t * 4; i < i1; i += 1024) {
        if (i + 3 < i1) {
            int4 d = *(const int4*)(dst + i);
            int4 s = *(const int4*)(src + i);
            int p;
            p = atomicAdd(&cur[d.x >> 6], 1); packed[p] = (int)(((unsigned)(d.x & 63) << 26) | (unsigned)s.x);
            p = atomicAdd(&cur[d.y >> 6], 1); packed[p] = (int)(((unsigned)(d.y & 63) << 26) | (unsigned)s.y);
            p = atomicAdd(&cur[d.z >> 6], 1); packed[p] = (int)(((unsigned)(d.z & 63) << 26) | (unsigned)s.z);
            p = atomicAdd(&cur[d.w >> 6], 1); packed[p] = (int)(((unsigned)(d.w & 63) << 26) | (unsigned)s.w);
        } else {
            for (int q = i; q < i1; ++q) {
                int dd = dst[q];
                int p = atomicAdd(&cur[dd >> 6], 1);
                packed[p] = (int)(((unsigned)(dd & 63) << 26) | (unsigned)src[q]);
            }
        }
    }
}

__global__ __launch_bounds__(256) void k_ellfill(const int* __restrict__ packed,
                                                 const int* __restrict__ chunkScan,
                                                 const int* __restrict__ chunkBase,
                                                 int* __restrict__ ell, int* __restrict__ cursor,
                                                 float* __restrict__ dinv,
                                                 int CAP, int NBKT, int N, int E) {
    __shared__ int ellLoc[64 * 96];
    __shared__ int cnt[64];
    int bkt = blockIdx.x, t = threadIdx.x;
    if (t < 64) cnt[t] = 0;
    __syncthreads();
    int l0 = bkt * 256;
    int bs = chunkScan[l0] + chunkBase[l0 >> 10];
    int be = E;
    if (bkt + 1 < NBKT) {
        int l1 = (bkt + 1) * 256;
        be = chunkScan[l1] + chunkBase[l1 >> 10];
    }
    for (int i = bs + t; i < be; i += 256) {
        unsigned p = (unsigned)packed[i];
        int s = (int)(p & 0x03FFFFFFu);
        int ld = (int)(p >> 26);
        int slot = atomicAdd(&cnt[ld], 1);
        if (slot < CAP) ellLoc[ld * CAP + slot] = s;
    }
    __syncthreads();
    int lo = bkt << 6;
    int total = 64 * CAP;
    for (int idx = t; idx < total; idx += 256) {
        int ld = idx / CAP;
        int s = idx - ld * CAP;
        if (lo + ld < N && s < min(cnt[ld], CAP))
            ell[(size_t)lo * CAP + idx] = ellLoc[idx];
    }
    if (t < 64 && lo + t < N) {
        int dg = min(cnt[t], CAP);
        cursor[lo + t] = (lo + t) * CAP + dg;
        dinv[lo + t] = rsqrtf(1.0f + (float)cnt[t]);
    }
}

// ================= fallback ELL build (atomic path) =================
__global__ __launch_bounds__(256) void k_cursor_init(int* cursor, int CAP, int n) {
    int i = blockIdx.x * 256 + threadIdx.x;
    if (i < n) cursor[i] = i * CAP;
}

__global__ __launch_bounds__(256) void k_fill_ell(const int* __restrict__ src, const int* __restrict__ dst,
                                                  int* cursor, int* __restrict__ ell, int E,
                                                  int lo, int hi) {
    int i = (blockIdx.x * 256 + threadIdx.x) * 4;
    if (i + 3 < E) {
        int4 d = *(const int4*)(dst + i);
        int4 s = *(const int4*)(src + i);
        if (d.x >= lo && d.x < hi) ell[atomicAdd(&cursor[d.x], 1)] = s.x;
        if (d.y >= lo && d.y < hi) ell[atomicAdd(&cursor[d.y], 1)] = s.y;
        if (d.z >= lo && d.z < hi) ell[atomicAdd(&cursor[d.z], 1)] = s.z;
        if (d.w >= lo && d.w < hi) ell[atomicAdd(&cursor[d.w], 1)] = s.w;
    } else {
        for (int t = i; t < E; ++t) {
            int d = dst[t];
            if (d >= lo && d < hi) ell[atomicAdd(&cursor[d], 1)] = src[t];
        }
    }
}

__global__ __launch_bounds__(256) void k_deg_dinv(const int* __restrict__ cursor, float* dinv, int CAP, int n) {
    int i = blockIdx.x * 256 + threadIdx.x;
    if (i < n) dinv[i] = rsqrtf(1.0f + (float)(cursor[i] - i * CAP));
}

// ---------------- MFMA GEMM: out[N][64](bf16) = (in[N][K] @ W[K][64] + bb) * dinv[row] ----------------
// Wave = 16-col tile (w*16..+15) x 4 row-tiles of 16. No LDS.
// A frag: row = lane&15 (+tile base), k = 32*kc + 8*(lane>>4) + e  -> 16B global load.
// B frag: col = lane&15 (+tile base), same k            -> 16B from Wb[col][K] (bf16 transposed).
// D frag: col = lane&15, row = (lane>>4)*4 + j  [HW-verified layout].
template <int K, bool AFP32>
__global__ __launch_bounds__(256) void gemm_mfma(const void* __restrict__ in_,
                                                 const unsigned short* __restrict__ Wb,
                                                 const float* __restrict__ bbv,
                                                 const float* __restrict__ dinv,
                                                 __hip_bfloat16* __restrict__ out, int N) {
    constexpr int NC = K / 32;
    int tid = threadIdx.x;
    int lane = tid & 63, w = tid >> 6;
    int r0 = blockIdx.x * 64;
    int col = w * 16 + (lane & 15);
    int kg = lane >> 4;  // 0..3

    // B fragments (per wave col-tile), L1-hot
    bf16x8 bfrag[NC];
#pragma unroll
    for (int kc = 0; kc < NC; ++kc)
        bfrag[kc] = *(const bf16x8*)(Wb + (size_t)col * K + kc * 32 + kg * 8);
    float bbc = bbv ? bbv[col] : 0.f;

#pragma unroll 1
    for (int rt = 0; rt < 4; ++rt) {
        int arow = r0 + rt * 16 + (lane & 15);
        int arow_c = min(arow, N - 1);
        f32x4 acc = {0.f, 0.f, 0.f, 0.f};
#pragma unroll
        for (int kc = 0; kc < NC; ++kc) {
            bf16x8 afrag;
            if (AFP32) {
                const float* in = (const float*)in_ + (size_t)arow_c * K + kc * 32 + kg * 8;
                float4 lo = *(const float4*)in;
                float4 hi = *(const float4*)(in + 4);
                union { short s[8]; bf16x8 v; } cv;
                cv.s[0] = bfb(lo.x); cv.s[1] = bfb(lo.y); cv.s[2] = bfb(lo.z); cv.s[3] = bfb(lo.w);
                cv.s[4] = bfb(hi.x); cv.s[5] = bfb(hi.y); cv.s[6] = bfb(hi.z); cv.s[7] = bfb(hi.w);
                afrag = cv.v;
            } else {
                const unsigned short* in = (const unsigned short*)in_;
                afrag = *(const bf16x8*)(in + (size_t)arow_c * K + kc * 32 + kg * 8);
            }
            acc = __builtin_amdgcn_mfma_f32_16x16x32_bf16(afrag, bfrag[kc], acc, 0, 0, 0);
        }
#pragma unroll
        for (int j = 0; j < 4; ++j) {
            int row = r0 + rt * 16 + kg * 4 + j;
            if (row < N)
                out[(size_t)row * 64 + col] = __float2bfloat16((acc[j] + bbc) * dinv[row]);
        }
    }
}

// pack W0[k][c] fp32 -> Wb0[c][k] bf16 (layer 0, K=128)
__global__ void k_packW0(const float* __restrict__ W0, unsigned short* __restrict__ Wb) {
    int c = threadIdx.x;  // 64 threads
    for (int k = 0; k < 128; ++k) Wb[c * 128 + k] = (unsigned short)bfb(W0[k * 64 + c]);
}

// ---------------- ELL pull: 8-lane group per node, static balanced slots ----------------
template <bool OUT_BF16>
__global__ __launch_bounds__(256, 4) void k_pull(const int* __restrict__ cursor,
                                                 const int* __restrict__ ell,
                                                 const float* __restrict__ dinv,
                                                 const uint4* __restrict__ xwh,  // 8 x uint4 per row
                                                 const float* __restrict__ bias,
                                                 float* __restrict__ aggf,
                                                 __hip_bfloat16* __restrict__ aggh,
                                                 float* __restrict__ sums, float* __restrict__ sumsq,
                                                 int CAP, int N) {
    int tid = threadIdx.x;
    int lane = tid & 63;
    int g = lane >> 3;   // group (node slot) 0..7
    int cl = lane & 7;   // channel slice
    float bs[8];
#pragma unroll
    for (int k = 0; k < 8; ++k) bs[k] = bias[cl * 8 + k];
    float s_acc[8] = {0, 0, 0, 0, 0, 0, 0, 0};
    float q_acc[8] = {0, 0, 0, 0, 0, 0, 0, 0};

    int slot = (blockIdx.x * 4 + (tid >> 6)) * 8 + g;
    int nslots = gridDim.x * 32;
    for (int n = slot; n < N; n += nslots) {
        int beg = n * CAP, end = cursor[n];
        int last = end - 1;
        float acc[8];
        {   // self row (already scaled by dinv[n])
            uint4 v = xwh[(size_t)n * 8 + cl];
            acc[0] = bf_lo(v.x); acc[1] = bf_hi(v.x);
            acc[2] = bf_lo(v.y); acc[3] = bf_hi(v.y);
            acc[4] = bf_lo(v.z); acc[5] = bf_hi(v.z);
            acc[6] = bf_lo(v.w); acc[7] = bf_hi(v.w);
        }
        int i = beg;
        for (; i + 8 <= end; i += 8) {  // full batches: no clamp/cndmask
            int4 ia = *(const int4*)&ell[i];
            int4 ib = *(const int4*)&ell[i + 4];
            uint4 vv[8];
            vv[0] = xwh[(size_t)ia.x * 8 + cl];
            vv[1] = xwh[(size_t)ia.y * 8 + cl];
            vv[2] = xwh[(size_t)ia.z * 8 + cl];
            vv[3] = xwh[(size_t)ia.w * 8 + cl];
            vv[4] = xwh[(size_t)ib.x * 8 + cl];
            vv[5] = xwh[(size_t)ib.y * 8 + cl];
            vv[6] = xwh[(size_t)ib.z * 8 + cl];
            vv[7] = xwh[(size_t)ib.w * 8 + cl];
#pragma unroll
            for (int k = 0; k < 8; ++k) {
                acc[0] += bf_lo(vv[k].x); acc[1] += bf_hi(vv[k].x);
                acc[2] += bf_lo(vv[k].y); acc[3] += bf_hi(vv[k].y);
                acc[4] += bf_lo(vv[k].z); acc[5] += bf_hi(vv[k].z);
                acc[6] += bf_lo(vv[k].w); acc[7] += bf_hi(vv[k].w);
            }
        }
        if (i < end) {  // tail batch (1..7 edges): clamp + zero
            int4 ia = *(const int4*)&ell[i];
            int4 ib = *(const int4*)&ell[i + 4];
            int ss[8];
            ss[0] = ia.x; ss[1] = ia.y; ss[2] = ia.z; ss[3] = ia.w;
            ss[4] = ib.x; ss[5] = ib.y; ss[6] = ib.z; ss[7] = ib.w;
#pragma unroll
            for (int k = 0; k < 8; ++k) ss[k] = (i + k <= last) ? ss[k] : 0;
            uint4 vv[8];
#pragma unroll
            for (int k = 0; k < 8; ++k) vv[k] = xwh[(size_t)ss[k] * 8 + cl];
#pragma unroll
            for (int k = 0; k < 8; ++k) {
                if (i + k > last) { vv[k].x = 0; vv[k].y = 0; vv[k].z = 0; vv[k].w = 0; }
                acc[0] += bf_lo(vv[k].x); acc[1] += bf_hi(vv[k].x);
                acc[2] += bf_lo(vv[k].y); acc[3] += bf_hi(vv[k].y);
                acc[4] += bf_lo(vv[k].z); acc[5] += bf_hi(vv[k].z);
                acc[6] += bf_lo(vv[k].w); acc[7] += bf_hi(vv[k].w);
            }
        }
        float dn = dinv[n];
        float r[8];
#pragma unroll
        for (int k = 0; k < 8; ++k) {
            r[k] = dn * acc[k] + bs[k];
            s_acc[k] += r[k];
            q_acc[k] += r[k] * r[k];
        }
        if (OUT_BF16) {
            uint4 o;
            o.x = pack_bf2(r[0], r[1]);
            o.y = pack_bf2(r[2], r[3]);
            o.z = pack_bf2(r[4], r[5]);
            o.w = pack_bf2(r[6], r[7]);
            *(uint4*)((unsigned short*)aggh + (size_t)n * 64 + cl * 8) = o;
        } else {
            float4* d4 = (float4*)(aggf + (size_t)n * 64 + cl * 8);
            d4[0] = make_float4(r[0], r[1], r[2], r[3]);
            d4[1] = make_float4(r[4], r[5], r[6], r[7]);
        }
    }

    // block-level stats reduce
    __shared__ float lsum[256][9], lsq[256][9];
#pragma unroll
    for (int k = 0; k < 8; ++k) { lsum[tid][k] = s_acc[k]; lsq[tid][k] = q_acc[k]; }
    __syncthreads();
    if (tid < 64) {
        int cl_t = tid >> 3, k_t = tid & 7;
        float s = 0.f, q = 0.f;
        for (int j = 0; j < 32; ++j) {
            int l = cl_t + 8 * j;
            s += lsum[l][k_t];
            q += lsq[l][k_t];
        }
        atomicAdd(&sums[tid], s);
        atomicAdd(&sumsq[tid], q);
    }
}

// ---------------- GraphNorm params + folded next-layer weights (bf16 transposed) + stat zeroing ----------------
__global__ void k_params2(float* __restrict__ sums, float* __restrict__ sumsq,
                          const float* __restrict__ alpha, const float* __restrict__ gamma,
                          const float* __restrict__ beta, const float* __restrict__ W,
                          float* __restrict__ scale, float* __restrict__ shift,
                          unsigned short* __restrict__ Wb, float* __restrict__ bb, int N) {
    __shared__ float ssc[64], ssh[64];
    int c = threadIdx.x;  // 64 threads
    float invN = 1.0f / (float)N;
    float m = sums[c] * invN;
    float ex2 = sumsq[c] * invN;
    float a = alpha[c];
    float var = ex2 - 2.0f * a * m * m + a * a * m * m;
    float sc = gamma[c] * rsqrtf(var + EPS);
    float sh = beta[c] - sc * a * m;
    scale[c] = sc;
    shift[c] = sh;
    ssc[c] = sc;
    ssh[c] = sh;
    sums[c] = 0.f;   // reset stats for next layer's pull
    sumsq[c] = 0.f;
    __syncthreads();
    if (W) {
        float acc = 0.f;
        for (int k = 0; k < 64; ++k) {
            float w = W[k * 64 + c];
            Wb[c * 64 + k] = (unsigned short)bfb(ssc[k] * w);  // transposed bf16
            acc += ssh[k] * w;
        }
        bb[c] = acc;
    }
}

__global__ __launch_bounds__(256) void k_final(float* __restrict__ out, const float* __restrict__ scale,
                                               const float* __restrict__ shift, int n64) {
    int i = blockIdx.x * 256 + threadIdx.x;
    if (i < n64) out[i] = scale[i & 63] * out[i] + shift[i & 63];
}

extern "C" void kernel_launch(void* const* d_in, const int* in_sizes, int n_in,
                              void* d_out, int out_size, void* d_ws, size_t ws_size,
                              hipStream_t stream) {
    const float* x     = (const float*)d_in[0];
    const int*   ei    = (const int*)d_in[1];
    const float* W0    = (const float*)d_in[2];
    const float* Wsp   = (const float*)d_in[3];
    const float* b     = (const float*)d_in[4];
    const float* alpha = (const float*)d_in[5];
    const float* gamma = (const float*)d_in[6];
    const float* beta  = (const float*)d_in[7];

    const int N = in_sizes[0] / 128;  // 100000
    const int E = in_sizes[1] / 2;    // 3200000
    const int* src = ei;
    const int* dst = ei + E;

    float* aggf = (float*)d_out;  // N*64 fp32: final-layer agg / output

    const int Na = ((N + 63) / 64) * 64;
    float* ws = (float*)d_ws;
    size_t off = 0;  // in 4-byte units
    float* dinv  = ws + off; off += Na;
    __hip_bfloat16* xwh = (__hip_bfloat16*)(ws + off); off += (size_t)Na * 32;  // N*64 bf16
    __hip_bfloat16* hb  = (__hip_bfloat16*)(ws + off); off += (size_t)Na * 32;  // N*64 bf16 agg (layers 0,1)
    float* sums  = ws + off; off += 64;
    float* sumsq = ws + off; off += 64;
    float* scbuf = ws + off; off += 64;
    float* shbuf = ws + off; off += 64;
    unsigned short* Wb = (unsigned short*)(ws + off); off += 4096;  // 64x128 bf16 max
    float* bbv   = ws + off; off += 64;
    int* cursor  = (int*)(ws + off); off += Na;

    int CAP = 96;
    while (CAP > 72 && (off + (size_t)N * CAP + 8) * 4 > ws_size) CAP -= 8;
    int* ell = (int*)(ws + off); off += (size_t)N * CAP + 8;

    const int n64 = N * 64;
    const int RB = (N + 63) / 64;
    const int NB = (N + 255) / 256;
    const int PB = (N + 63) / 64;  // k_pull: 2 nodes/slot

    // ----- ELL build: scan-based radix partition (no global atomics) -----
    const int NBKT = (N + 63) >> 6;
    const int NSEG = 256;
    int SEG = ((E + NSEG - 1) / NSEG + 3) & ~3;
    const int SCAN_N = NBKT * 256;
    const int NCH = (SCAN_N + 1023) / 1024;
    int* packed    = (int*)xwh;
    int* hist      = (int*)hb;
    int* chunkScan = hist + (size_t)NSEG * NBKT;
    int* chunkTot  = chunkScan + (size_t)NCH * 1024;
    int* chunkBase = chunkTot + NCH;
    bool fast_build = (NBKT <= 2048) && (NCH <= 512) && (N < (1 << 26)) &&
                      ((size_t)E <= (size_t)Na * 32) &&
                      ((size_t)NSEG * NBKT + (size_t)NCH * 1024 + 2 * NCH <= (size_t)Na * 32);

    if (fast_build) {
        k_hist<<<NSEG, 256, 0, stream>>>(dst, hist, E, SEG, NBKT);
        k_scanA<<<NCH, 256, 0, stream>>>(hist, chunkScan, chunkTot, NBKT, SCAN_N);
        k_scanB<<<1, 256, 0, stream>>>(chunkTot, chunkBase, NCH);
        k_scatter_part<<<NSEG, 256, 0, stream>>>(src, dst, chunkScan, chunkBase, packed, E, SEG, NBKT);
        k_ellfill<<<NBKT, 256, 0, stream>>>(packed, chunkScan, chunkBase, ell, cursor, dinv,
                                            CAP, NBKT, N, E);
    } else {
        k_cursor_init<<<NB, 256, 0, stream>>>(cursor, CAP, N);
        const int NCHUNK = 10;
        int cs = (N + NCHUNK - 1) / NCHUNK;
        const int EB4 = (E / 4 + 255) / 256;
        for (int c = 0; c < NCHUNK; ++c) {
            int lo = c * cs, hi = min(N, lo + cs);
            k_fill_ell<<<EB4, 256, 0, stream>>>(src, dst, cursor, ell, E, lo, hi);
        }
        k_deg_dinv<<<NB, 256, 0, stream>>>(cursor, dinv, CAP, N);
    }

    // stats zero once; k_params2 re-zeroes for subsequent layers
    hipMemsetAsync(sums, 0, 128 * sizeof(float), stream);
    k_packW0<<<1, 64, 0, stream>>>(W0, Wb);

    // ----- 3 layers -----
    for (int layer = 0; layer < 3; ++layer) {
        if (layer == 0) {
            gemm_mfma<128, true><<<RB, 256, 0, stream>>>(x, Wb, nullptr, dinv, xwh, N);
        } else {
            gemm_mfma<64, false><<<RB, 256, 0, stream>>>(hb, Wb, bbv, dinv, xwh, N);
        }
        if (layer < 2) {
            k_pull<true><<<PB, 256, 0, stream>>>(cursor, ell, dinv, (const uint4*)xwh,
                                                 b + layer * 64, nullptr, hb,
                                                 sums, sumsq, CAP, N);
        } else {
            k_pull<false><<<PB, 256, 0, stream>>>(cursor, ell, dinv, (const uint4*)xwh,
                                                  b + layer * 64, aggf, nullptr,
                                                  sums, sumsq, CAP, N);
        }
        const float* Wnext = (layer < 2) ? (Wsp + (size_t)layer * 64 * 64) : nullptr;
        k_params2<<<1, 64, 0, stream>>>(sums, sumsq, alpha + layer * 64, gamma + layer * 64,
                                        beta + layer * 64, Wnext, scbuf, shbuf, Wb, bbv, N);
    }
    k_final<<<(n64 + 255) / 256, 256, 0, stream>>>(aggf, scbuf, shbuf, n64);
}